// Round 9
// baseline (5395.439 us; speedup 1.0000x reference)
//
#include <hip/hip_runtime.h>
#include <math.h>

#define TS 64
#define IFACE_N 471
#define EPS_ 1e-6f

// iface column offsets
#define OFF_RK 0
#define OFF_RB 256
#define OFF_WK 260
#define OFF_WB 324
#define OFF_EV 325
#define OFF_WV 389
#define OFF_FG 453
#define OFF_AG 457
#define OFF_WG 458
#define OFF_RM 459

// ws float offsets
#define O_HX   0         // 524288 : hx = x@W_hid[0:512]+b (64*16 x 512)
#define O_H    524288    // 16384  : h ping-pong (2 x 16 x 512)
#define O_RV   540672    // 8192   : rv ping-pong (2 x 16 x 256)
#define O_M    548864    // 262144
#define O_L    811008    // 1048576
#define O_FLG  1859584   // 768 ints
// packed bf16 weights (uint = 2 k-rows):
#define O_WIP  1860352   // 120576 uints (256 kp x 471)  W_iface
#define O_WHP  1981184   // 65536  uints (128 kp x 512)  W_hid[512:768]
#define O_WOP  2046720   // 131072 uints (256 kp x 512)  W_out
#define O_WMP  2177792   // 65536  uints (128 kp x 512)  W_memout
// total 2,243,328 floats = 8.97 MB (< R1's proven 9.88 MB)

__device__ __forceinline__ float sigmoidf_(float x){ return 1.f/(1.f+expf(-x)); }
__device__ __forceinline__ float oneplusf_(float x){ return 1.f+fmaxf(x,0.f)+log1pf(expf(-fabsf(x))); }
__device__ __forceinline__ float wsum_(float v){
#pragma unroll
  for(int off=32; off>0; off>>=1) v += __shfl_xor(v,off,64);
  return v;
}
__device__ __forceinline__ float wmax_(float v){
#pragma unroll
  for(int off=32; off>0; off>>=1) v = fmaxf(v,__shfl_xor(v,off,64));
  return v;
}
__device__ __forceinline__ void waitge_(int* f, int v){
  while (__hip_atomic_load(f, __ATOMIC_ACQUIRE, __HIP_MEMORY_SCOPE_AGENT) < v) {}
}
__device__ __forceinline__ void publish_(int* f, int v){
  __threadfence();
  __hip_atomic_store(f, v, __ATOMIC_RELEASE, __HIP_MEMORY_SCOPE_AGENT);
}
__device__ __forceinline__ unsigned bf16rne_(float f){
  unsigned u = __float_as_uint(f);
  return (u + 0x7FFFu + ((u >> 16) & 1u)) >> 16;
}
__device__ __forceinline__ unsigned bf16pack_(float lo, float hi){
  return bf16rne_(lo) | (bf16rne_(hi) << 16);
}
__device__ __forceinline__ float bflo_(unsigned p){ return __uint_as_float(p << 16); }
__device__ __forceinline__ float bfhi_(unsigned p){ return __uint_as_float(p & 0xFFFF0000u); }

// ===================== init =====================
__global__ void __launch_bounds__(256) kInit(float* ws){
  int g = blockIdx.x*256 + threadIdx.x;          // 65536 threads
  int* fl = (int*)(ws + O_FLG);
  if (g < 768) fl[g] = (g < 256 && (g & 15) == 0) ? 1 : 0;   // hflag=1 (h(0) via kPre)
  for (int i=g;i<262144;i+=65536) ws[O_M+i]=1e-6f;
  for (int i=g;i<1048576;i+=65536) ws[O_L+i]=0.f;
}

// ===================== kConv: pack streamed weights to bf16 pairs =====================
__global__ void __launch_bounds__(256)
kConv(const float* __restrict__ W_hid, const float* __restrict__ W_iface,
      const float* __restrict__ W_out, const float* __restrict__ W_memout,
      float* __restrict__ ws)
{
  unsigned* Wip = (unsigned*)(ws + O_WIP);
  unsigned* Whp = (unsigned*)(ws + O_WHP);
  unsigned* Wop = (unsigned*)(ws + O_WOP);
  unsigned* Wmp = (unsigned*)(ws + O_WMP);
  int g = blockIdx.x*256 + threadIdx.x;          // 65536 threads
  for (int i = g; i < 120576; i += 65536) {
    int kp = i / 471, c = i - kp*471;
    Wip[i] = bf16pack_(W_iface[(size_t)(2*kp)*IFACE_N + c],
                       W_iface[(size_t)(2*kp+1)*IFACE_N + c]);
  }
  {
    int kp = g >> 9, c = g & 511;
    Whp[g] = bf16pack_(W_hid[(size_t)(512 + 2*kp)*512 + c],
                       W_hid[(size_t)(513 + 2*kp)*512 + c]);
  }
  for (int i = g; i < 131072; i += 65536) {
    int kp = i >> 9, c = i & 511;
    Wop[i] = bf16pack_(W_out[(size_t)(2*kp)*512 + c], W_out[(size_t)(2*kp+1)*512 + c]);
  }
  {
    int kp = g >> 9, c = g & 511;
    Wmp[g] = bf16pack_(W_memout[(size_t)(2*kp)*512 + c], W_memout[(size_t)(2*kp+1)*512 + c]);
  }
}

// ===================== kPre: hx = x @ W_hid[0:512] + b ; h(0) =====================
__global__ void __launch_bounds__(256)
kPre(const float* __restrict__ x, const float* __restrict__ W_hid,
     const float* __restrict__ b_hid, float* __restrict__ ws)
{
  const int tid = threadIdx.x, blk = blockIdx.x;
  const int r0 = (blk >> 1) * 8, col = (blk & 1) * 256 + tid;
  __shared__ float xs[8][512];
  for (int i = tid; i < 8*512; i += 256) {
    int rr = i >> 9, k = i & 511;
    xs[rr][k] = x[(size_t)(r0+rr)*512 + k];
  }
  __syncthreads();
  float a0=0,a1=0,a2=0,a3=0,a4=0,a5=0,a6=0,a7=0;
  const float* Wp = W_hid + col;
#pragma unroll 4
  for (int k = 0; k < 512; k++) {
    float w = Wp[(size_t)k*512];
    a0 = fmaf(xs[0][k], w, a0); a1 = fmaf(xs[1][k], w, a1);
    a2 = fmaf(xs[2][k], w, a2); a3 = fmaf(xs[3][k], w, a3);
    a4 = fmaf(xs[4][k], w, a4); a5 = fmaf(xs[5][k], w, a5);
    a6 = fmaf(xs[6][k], w, a6); a7 = fmaf(xs[7][k], w, a7);
  }
  float bh = b_hid[col];
  float av[8] = {a0,a1,a2,a3,a4,a5,a6,a7};
#pragma unroll
  for (int i = 0; i < 8; i++) {
    int r = r0 + i;
    float v = av[i] + bh;
    ws[O_HX + (size_t)r*512 + col] = v;
    if (r < 16) ws[O_H + r*512 + col] = fmaxf(v, 0.f);   // h(0), slot 0
  }
}

// ===================== kRun: persistent, 16 batch + 16 out-helper blocks ==========
__global__ void __launch_bounds__(1024, 4)
kRun(float* __restrict__ ws, float* __restrict__ out)
{
  const int tid = threadIdx.x, blk = blockIdx.x;
  const int wv = tid >> 6, lane = tid & 63;
  int* fl = (int*)(ws + O_FLG);
  const unsigned* Wip = (const unsigned*)(ws + O_WIP);
  const unsigned* Whp = (const unsigned*)(ws + O_WHP);
  const unsigned* Wop = (const unsigned*)(ws + O_WOP);
  const unsigned* Wmp = (const unsigned*)(ws + O_WMP);

  __shared__ float hl[512];
  __shared__ float ifcl[480];
  __shared__ float psum[1024];
  __shared__ float ul[256], pOl[256], pNl[256], wwl[256];
  __shared__ float rwl[1024];
  __shared__ float wkn[64], rknl[256];
  __shared__ alignas(16) float evl[64], wvl[64];
  __shared__ float ssorted[256];
  __shared__ int   sidx[256];
  __shared__ float sal[256], siml[256];
  __shared__ float fwdl[1024], bwdl[1024], rcs[1024];
  __shared__ alignas(16) float bb[16][260];
  __shared__ float rvl[256];

  if (blk >= 16) {
    // ================= out-helper: out(t) = h(t)@W_out + rv(t)@W_memout =====
    const int b = blk - 16;
    int* hfl = fl + b*16; int* rfl = fl + 256 + b*16; int* ofl = fl + 512 + b*16;
    for (int t = 0; t < TS; t++) {
      if (tid == 0) { waitge_(hfl, t+1); waitge_(rfl, t+1); }
      __syncthreads();
      if (tid < 512)      hl[tid] = ws[O_H + (t&1)*8192 + b*512 + tid];
      else if (tid < 768) rvl[tid-512] = ws[O_RV + (t&1)*4096 + b*256 + (tid-512)];
      __syncthreads();
      int col = tid & 511, kseg = tid >> 9;
      const unsigned* Wo = Wop + (size_t)(kseg*128)*512 + col;
      const float* hp = hl + kseg*256;
      float acc = 0.f;
#pragma unroll 8
      for (int kp = 0; kp < 128; kp++) {
        unsigned p = Wo[(size_t)kp*512];
        acc = fmaf(hp[2*kp],   bflo_(p), acc);
        acc = fmaf(hp[2*kp+1], bfhi_(p), acc);
      }
      const unsigned* Wm = Wmp + (size_t)(kseg*64)*512 + col;
      const float* rp = rvl + kseg*128;
#pragma unroll 8
      for (int kp = 0; kp < 64; kp++) {
        unsigned p = Wm[(size_t)kp*512];
        acc = fmaf(rp[2*kp],   bflo_(p), acc);
        acc = fmaf(rp[2*kp+1], bfhi_(p), acc);
      }
      psum[tid] = acc;
      __syncthreads();
      if (tid < 512) out[(size_t)t*8192 + b*512 + tid] = psum[tid] + psum[512+tid];
      __syncthreads();
      if (tid == 0) publish_(ofl, t+1);
    }
    return;
  }

  // ================= batch block =================
  const int b = blk;
  float* Mg = ws + O_M + (size_t)b*16384;
  float* Lg = ws + O_L + (size_t)b*65536;
  int* ofl = fl + 512 + b*16;
  int* hfl = fl + b*16; int* rfl = fl + 256 + b*16;

  if (tid < 512) hl[tid] = ws[O_H + b*512 + tid];     // h(0), slot 0
  rwl[tid] = 0.f;
  if (tid < 256){ ul[tid]=0.f; pOl[tid]=0.f; wwl[tid]=0.f; }
  __syncthreads();

  for (int t = 0; t < TS; t++) {
    // ---- iface = h @ W_iface (bf16-pair, k-split 2) ----
    {
      int col = tid & 511, kseg = tid >> 9;
      float acc = 0.f;
      if (col < IFACE_N) {
        const unsigned* Wp = Wip + (size_t)(kseg*128)*IFACE_N + col;
        const float* hp = hl + kseg*256;
#pragma unroll 8
        for (int kp = 0; kp < 128; kp++) {
          unsigned p = Wp[(size_t)kp*IFACE_N];
          acc = fmaf(hp[2*kp],   bflo_(p), acc);
          acc = fmaf(hp[2*kp+1], bfhi_(p), acc);
        }
      }
      psum[tid] = acc;
    }
    __syncthreads();
    if (tid < IFACE_N) ifcl[tid] = psum[tid] + psum[512+tid];
    __syncthreads();

    // ---- usage update + key norms + gate vectors ----
    if (tid < 256) {
      float ret = 1.f;
#pragma unroll
      for (int r = 0; r < 4; r++) {
        float fg = sigmoidf_(ifcl[OFF_FG + r]);
        ret *= (1.f - fg * rwl[r*256 + tid]);
      }
      float uo = ul[tid], wo = wwl[tid];
      ul[tid] = (uo + wo - uo*wo) * ret;
    } else if (tid >= 448 && tid < 512) {              // wave 7: wk norm
      float kv = ifcl[OFF_WK + lane];
      float ss = wsum_(kv*kv);
      wkn[lane] = kv / (sqrtf(ss) + EPS_);
    } else if (tid >= 512 && tid < 768) {              // waves 8..11: rk norms
      int r = wv - 8;
      float kv = ifcl[OFF_RK + r*64 + lane];
      float ss = wsum_(kv*kv);
      rknl[r*64 + lane] = kv / (sqrtf(ss) + EPS_);
    } else if (tid >= 768 && tid < 832) {              // wave 12: erase vec
      evl[lane] = sigmoidf_(ifcl[OFF_EV + lane]);
    } else if (tid >= 832 && tid < 896) {              // wave 13: write vec
      wvl[lane] = ifcl[OFF_WV + lane];
    }
    __syncthreads();

    // ---- stable rank argsort + cumprod alloc ----
    {
      int n = tid >> 2, q = tid & 3;
      float un = ul[n];
      const float* sp = ul + q*64;
      int cnt = 0;
#pragma unroll 8
      for (int m = 0; m < 64; m++) {
        float um = sp[m];
        int gm = q*64 + m;
        cnt += (um < un || (um == un && gm < n)) ? 1 : 0;
      }
      cnt += __shfl_xor(cnt, 1, 64);
      cnt += __shfl_xor(cnt, 2, 64);
      if (q == 0) { ssorted[cnt] = un; sidx[cnt] = n; }
    }
    __syncthreads();
    if (wv == 0) {
      float carry = 1.f;
#pragma unroll
      for (int c2 = 0; c2 < 4; c2++) {
        float v0 = ssorted[c2*64 + lane];
        float v = v0;
#pragma unroll
        for (int off = 1; off < 64; off <<= 1) {
          float uu = __shfl_up(v, off, 64);
          if (lane >= off) v *= uu;
        }
        float e = __shfl_up(v, 1, 64);
        if (lane == 0) e = 1.f;
        sal[sidx[c2*64 + lane]] = (1.f - v0) * e * carry;
        carry *= __shfl(v, 63, 64);
      }
    }
    __syncthreads();

    // ---- write content weights over OLD M ----
    {
      int n = tid >> 2, q = tid & 3;
      const float4* Mp = (const float4*)(Mg + n*64 + q*16);
      float ss = 0.f, dt = 0.f;
#pragma unroll
      for (int i = 0; i < 4; i++) {
        float4 mv = Mp[i];
        const float* kp = wkn + q*16 + i*4;
        ss += mv.x*mv.x + mv.y*mv.y + mv.z*mv.z + mv.w*mv.w;
        dt += mv.x*kp[0] + mv.y*kp[1] + mv.z*kp[2] + mv.w*kp[3];
      }
      ss += __shfl_xor(ss,1,64); ss += __shfl_xor(ss,2,64);
      dt += __shfl_xor(dt,1,64); dt += __shfl_xor(dt,2,64);
      if (q == 0) {
        float wb = oneplusf_(ifcl[OFF_WB]);
        siml[n] = wb * dt / (sqrtf(ss) + EPS_);
      }
    }
    __syncthreads();
    if (tid < 256) {
      float v0 = siml[lane], v1 = siml[64+lane], v2 = siml[128+lane], v3 = siml[192+lane];
      float mx = wmax_(fmaxf(fmaxf(v0,v1), fmaxf(v2,v3)));
      float ssum = wsum_(expf(v0-mx)+expf(v1-mx)+expf(v2-mx)+expf(v3-mx));
      float cw = expf(siml[tid]-mx) / ssum;
      float ag = sigmoidf_(ifcl[OFF_AG]);
      float wg = sigmoidf_(ifcl[OFF_WG]);
      wwl[tid] = wg * (ag*sal[tid] + (1.f-ag)*cw);
      ssorted[tid] = wwl[tid];
    }
    __syncthreads();
    if (tid < 256) {
      float s4 = ssorted[lane] + ssorted[64+lane] + ssorted[128+lane] + ssorted[192+lane];
      float wws = wsum_(s4);
      pNl[tid] = (1.f - wws)*pOl[tid] + wwl[tid];
    }
    __syncthreads();

    // ---- L update + fwd + bwd ----
    {
      int j0 = lane*4;
      float wwj0 = wwl[j0], wwj1 = wwl[j0+1], wwj2 = wwl[j0+2], wwj3 = wwl[j0+3];
      float pj0 = pOl[j0], pj1 = pOl[j0+1], pj2 = pOl[j0+2], pj3 = pOl[j0+3];
      float rw00 = rwl[j0],     rw01 = rwl[j0+1],     rw02 = rwl[j0+2],     rw03 = rwl[j0+3];
      float rw10 = rwl[256+j0], rw11 = rwl[256+j0+1], rw12 = rwl[256+j0+2], rw13 = rwl[256+j0+3];
      float rw20 = rwl[512+j0], rw21 = rwl[512+j0+1], rw22 = rwl[512+j0+2], rw23 = rwl[512+j0+3];
      float rw30 = rwl[768+j0], rw31 = rwl[768+j0+1], rw32 = rwl[768+j0+2], rw33 = rwl[768+j0+3];
      float4 ba0 = {0,0,0,0}, ba1 = {0,0,0,0}, ba2 = {0,0,0,0}, ba3 = {0,0,0,0};
      float4* Lrow = (float4*)Lg;
#pragma unroll 4
      for (int ii = 0; ii < 16; ii++) {
        int i = wv*16 + ii;
        float wwi = wwl[i];
        float4 lv = Lrow[i*64 + lane];
        float4 nv;
        nv.x = (1.f - wwi - wwj0)*lv.x + wwi*pj0;
        nv.y = (1.f - wwi - wwj1)*lv.y + wwi*pj1;
        nv.z = (1.f - wwi - wwj2)*lv.z + wwi*pj2;
        nv.w = (1.f - wwi - wwj3)*lv.w + wwi*pj3;
        if (j0   == i) nv.x = 0.f;
        if (j0+1 == i) nv.y = 0.f;
        if (j0+2 == i) nv.z = 0.f;
        if (j0+3 == i) nv.w = 0.f;
        Lrow[i*64 + lane] = nv;
        float f0 = nv.x*rw00 + nv.y*rw01 + nv.z*rw02 + nv.w*rw03;
        float f1 = nv.x*rw10 + nv.y*rw11 + nv.z*rw12 + nv.w*rw13;
        float f2 = nv.x*rw20 + nv.y*rw21 + nv.z*rw22 + nv.w*rw23;
        float f3 = nv.x*rw30 + nv.y*rw31 + nv.z*rw32 + nv.w*rw33;
        f0 = wsum_(f0); f1 = wsum_(f1); f2 = wsum_(f2); f3 = wsum_(f3);
        if (lane == 0) { fwdl[i] = f0; fwdl[256+i] = f1; fwdl[512+i] = f2; fwdl[768+i] = f3; }
        float ri0 = rwl[i], ri1 = rwl[256+i], ri2 = rwl[512+i], ri3 = rwl[768+i];
        ba0.x = fmaf(ri0, nv.x, ba0.x); ba0.y = fmaf(ri0, nv.y, ba0.y);
        ba0.z = fmaf(ri0, nv.z, ba0.z); ba0.w = fmaf(ri0, nv.w, ba0.w);
        ba1.x = fmaf(ri1, nv.x, ba1.x); ba1.y = fmaf(ri1, nv.y, ba1.y);
        ba1.z = fmaf(ri1, nv.z, ba1.z); ba1.w = fmaf(ri1, nv.w, ba1.w);
        ba2.x = fmaf(ri2, nv.x, ba2.x); ba2.y = fmaf(ri2, nv.y, ba2.y);
        ba2.z = fmaf(ri2, nv.z, ba2.z); ba2.w = fmaf(ri2, nv.w, ba2.w);
        ba3.x = fmaf(ri3, nv.x, ba3.x); ba3.y = fmaf(ri3, nv.y, ba3.y);
        ba3.z = fmaf(ri3, nv.z, ba3.z); ba3.w = fmaf(ri3, nv.w, ba3.w);
      }
#pragma unroll
      for (int r = 0; r < 4; r++) {
        float4 v = (r==0) ? ba0 : (r==1) ? ba1 : (r==2) ? ba2 : ba3;
        *(float4*)&bb[wv][j0] = v;
        __syncthreads();
        if (tid < 256) {
          float s = 0.f;
#pragma unroll
          for (int w2 = 0; w2 < 16; w2++) s += bb[w2][tid];
          bwdl[r*256 + tid] = s;
        }
        __syncthreads();
      }
    }
    if (tid < 256) pOl[tid] = pNl[tid];   // p for next step (L-update done)

    // ---- M update + rc logits (NEW M) ----
    {
      int n = tid >> 2, q = tid & 3;
      float wwn = wwl[n];
      float4* Mp = (float4*)(Mg + n*64 + q*16);
      float ss = 0.f, d0 = 0.f, d1 = 0.f, d2 = 0.f, d3 = 0.f;
#pragma unroll
      for (int i = 0; i < 4; i++) {
        float4 mv = Mp[i];
        int w0 = q*16 + i*4;
        float4 ev = *(const float4*)(evl + w0);
        float4 wq = *(const float4*)(wvl + w0);
        float4 nv;
        nv.x = mv.x*(1.f - wwn*ev.x) + wwn*wq.x;
        nv.y = mv.y*(1.f - wwn*ev.y) + wwn*wq.y;
        nv.z = mv.z*(1.f - wwn*ev.z) + wwn*wq.z;
        nv.w = mv.w*(1.f - wwn*ev.w) + wwn*wq.w;
        Mp[i] = nv;
        ss += nv.x*nv.x + nv.y*nv.y + nv.z*nv.z + nv.w*nv.w;
        const float* k0 = rknl + w0;
        const float* k1 = rknl + 64 + w0;
        const float* k2 = rknl + 128 + w0;
        const float* k3 = rknl + 192 + w0;
        d0 += nv.x*k0[0] + nv.y*k0[1] + nv.z*k0[2] + nv.w*k0[3];
        d1 += nv.x*k1[0] + nv.y*k1[1] + nv.z*k1[2] + nv.w*k1[3];
        d2 += nv.x*k2[0] + nv.y*k2[1] + nv.z*k2[2] + nv.w*k2[3];
        d3 += nv.x*k3[0] + nv.y*k3[1] + nv.z*k3[2] + nv.w*k3[3];
      }
      ss += __shfl_xor(ss,1,64); ss += __shfl_xor(ss,2,64);
      d0 += __shfl_xor(d0,1,64); d0 += __shfl_xor(d0,2,64);
      d1 += __shfl_xor(d1,1,64); d1 += __shfl_xor(d1,2,64);
      d2 += __shfl_xor(d2,1,64); d2 += __shfl_xor(d2,2,64);
      d3 += __shfl_xor(d3,1,64); d3 += __shfl_xor(d3,2,64);
      if (q == 0) {
        float inv = 1.f/(sqrtf(ss) + EPS_);
        rcs[n]     = oneplusf_(ifcl[OFF_RB+0]) * d0 * inv;
        rcs[256+n] = oneplusf_(ifcl[OFF_RB+1]) * d1 * inv;
        rcs[512+n] = oneplusf_(ifcl[OFF_RB+2]) * d2 * inv;
        rcs[768+n] = oneplusf_(ifcl[OFF_RB+3]) * d3 * inv;
      }
    }
    __syncthreads();

    // ---- rc softmax ----
    if (wv < 4) {
      float* rp = rcs + wv*256;
      float v0 = rp[lane], v1 = rp[64+lane], v2 = rp[128+lane], v3 = rp[192+lane];
      float mx = wmax_(fmaxf(fmaxf(v0,v1), fmaxf(v2,v3)));
      float e0 = expf(v0-mx), e1 = expf(v1-mx), e2 = expf(v2-mx), e3 = expf(v3-mx);
      float inv = 1.f / wsum_(e0+e1+e2+e3);
      rp[lane] = e0*inv; rp[64+lane] = e1*inv; rp[128+lane] = e2*inv; rp[192+lane] = e3*inv;
    }
    __syncthreads();

    // ---- rw_new ----
    {
      int r = tid >> 8;
      float e0 = ifcl[OFF_RM + r*3+0], e1 = ifcl[OFF_RM + r*3+1], e2 = ifcl[OFF_RM + r*3+2];
      float mx = fmaxf(e0, fmaxf(e1, e2));
      float x0 = expf(e0-mx), x1 = expf(e1-mx), x2 = expf(e2-mx);
      float inv = 1.f/(x0+x1+x2);
      rwl[tid] = (x0*bwdl[tid] + x1*rcs[tid] + x2*fwdl[tid]) * inv;
    }
    __syncthreads();

    // ---- rv_new ----
    {
      int w = tid & 63, r = (tid >> 6) & 3, c = tid >> 8;
      const float* rp = rwl + r*256 + c*64;
      float acc = 0.f;
#pragma unroll 8
      for (int n = 0; n < 64; n++) acc = fmaf(Mg[(c*64+n)*64 + w], rp[n], acc);
      psum[c*256 + r*64 + w] = acc;
    }
    __syncthreads();
    if (tid < 256)
      rvl[tid] = psum[tid] + psum[256+tid] + psum[512+tid] + psum[768+tid];

    // ---- publish rv(t) (slot t&1; prior occupant rv(t-2) consumed by out(t-2)) ----
    if (tid == 0) waitge_(ofl, t-1);
    __syncthreads();
    if (tid < 256) ws[O_RV + (t&1)*4096 + b*256 + tid] = rvl[tid];
    __syncthreads();
    if (tid == 0) publish_(rfl, t+1);

    // ---- h(t+1) = relu(hx(t+1) + rv @ W_hid[512:768] bf16) ----
    if (t + 1 < TS) {
      if (tid == 0) waitge_(ofl, t);   // slot (t+1)&1 held h(t-1), consumed by out(t-1)
      __syncthreads();
      int col = tid & 511, kseg = tid >> 9;
      const unsigned* Wp = Whp + (size_t)(kseg*64)*512 + col;
      const float* rp = rvl + kseg*128;
      float acc = 0.f;
#pragma unroll 8
      for (int kp = 0; kp < 64; kp++) {
        unsigned p = Wp[(size_t)kp*512];
        acc = fmaf(rp[2*kp],   bflo_(p), acc);
        acc = fmaf(rp[2*kp+1], bfhi_(p), acc);
      }
      psum[tid] = acc;
      __syncthreads();
      if (tid < 512) {
        float v = ws[O_HX + (size_t)((t+1)*16 + b)*512 + tid] + psum[tid] + psum[512+tid];
        v = fmaxf(v, 0.f);
        hl[tid] = v;
        ws[O_H + ((t+1)&1)*8192 + b*512 + tid] = v;
      }
      __syncthreads();
      if (tid == 0) publish_(hfl, t+2);
    }
  }
}

extern "C" void kernel_launch(void* const* d_in, const int* in_sizes, int n_in,
                              void* d_out, int out_size, void* d_ws, size_t ws_size,
                              hipStream_t stream) {
  (void)in_sizes; (void)n_in; (void)out_size; (void)ws_size;
  const float* x        = (const float*)d_in[0];
  const float* W_hid    = (const float*)d_in[1];
  const float* b_hid    = (const float*)d_in[2];
  const float* W_iface  = (const float*)d_in[3];
  const float* W_out    = (const float*)d_in[4];
  const float* W_memout = (const float*)d_in[5];
  float* outp = (float*)d_out;
  float* ws   = (float*)d_ws;

  hipLaunchKernelGGL(kInit, dim3(256), dim3(256), 0, stream, ws);
  hipLaunchKernelGGL(kConv, dim3(256), dim3(256), 0, stream,
                     W_hid, W_iface, W_out, W_memout, ws);
  hipLaunchKernelGGL(kPre,  dim3(256), dim3(256), 0, stream, x, W_hid, b_hid, ws);
  void* args[] = {&ws, &outp};
  hipLaunchCooperativeKernel((void*)kRun, dim3(32), dim3(1024), args, 0, stream);
}

// Round 10
// 4274.944 us; speedup vs baseline: 1.2621x; 1.2621x over previous
//
#include <hip/hip_runtime.h>
#include <math.h>

#define TS 64
#define IFACE_N 471
#define EPS_ 1e-6f

// iface column offsets
#define OFF_RK 0
#define OFF_RB 256
#define OFF_WK 260
#define OFF_WB 324
#define OFF_EV 325
#define OFF_WV 389
#define OFF_FG 453
#define OFF_AG 457
#define OFF_WG 458
#define OFF_RM 459

// ws float offsets
#define O_HX   0         // 524288 : hx = x@W_hid[0:512]+b (64*16 x 512)
#define O_H    524288    // 16384  : h ping-pong (2 x 16 x 512)
#define O_RV   540672    // 8192   : rv ping-pong (2 x 16 x 256)
#define O_M    548864    // 262144
#define O_L    811008    // 1048576
#define O_FLG  1859584   // 768 ints
// packed bf16 weights, TRANSPOSED thread-contiguous [col][kpair], padded strides:
#define WIPS 260
#define WHPS 132
#define WOPS 260
#define WMPS 132
#define O_WIP  1860352   // 471*260 = 122460 uints   W_iface  (256 kp)
#define O_WHP  1982812   // 512*132 = 67584          W_hid[512:768] (128 kp)
#define O_WOP  2050396   // 512*260 = 133120         W_out (256 kp)
#define O_WMP  2183516   // 512*132 = 67584          W_memout (128 kp)
// total 2,251,100 floats = 9.00 MB

__device__ __forceinline__ float sigmoidf_(float x){ return 1.f/(1.f+expf(-x)); }
__device__ __forceinline__ float oneplusf_(float x){ return 1.f+fmaxf(x,0.f)+log1pf(expf(-fabsf(x))); }
__device__ __forceinline__ float wsum_(float v){
#pragma unroll
  for(int off=32; off>0; off>>=1) v += __shfl_xor(v,off,64);
  return v;
}
__device__ __forceinline__ float wmax_(float v){
#pragma unroll
  for(int off=32; off>0; off>>=1) v = fmaxf(v,__shfl_xor(v,off,64));
  return v;
}
__device__ __forceinline__ void waitge_(int* f, int v){
  while (__hip_atomic_load(f, __ATOMIC_ACQUIRE, __HIP_MEMORY_SCOPE_AGENT) < v) {}
}
__device__ __forceinline__ void publish_(int* f, int v){
  __threadfence();
  __hip_atomic_store(f, v, __ATOMIC_RELEASE, __HIP_MEMORY_SCOPE_AGENT);
}
__device__ __forceinline__ unsigned bf16rne_(float f){
  unsigned u = __float_as_uint(f);
  return (u + 0x7FFFu + ((u >> 16) & 1u)) >> 16;
}
__device__ __forceinline__ unsigned bf16pack_(float lo, float hi){
  return bf16rne_(lo) | (bf16rne_(hi) << 16);
}
__device__ __forceinline__ float bflo_(unsigned p){ return __uint_as_float(p << 16); }
__device__ __forceinline__ float bfhi_(unsigned p){ return __uint_as_float(p & 0xFFFF0000u); }

// dot of one uint4 (8 bf16 k-rows) against 8 consecutive activations
__device__ __forceinline__ float dot8_(uint4 p, const float* a, float acc){
  acc = fmaf(a[0], bflo_(p.x), acc); acc = fmaf(a[1], bfhi_(p.x), acc);
  acc = fmaf(a[2], bflo_(p.y), acc); acc = fmaf(a[3], bfhi_(p.y), acc);
  acc = fmaf(a[4], bflo_(p.z), acc); acc = fmaf(a[5], bfhi_(p.z), acc);
  acc = fmaf(a[6], bflo_(p.w), acc); acc = fmaf(a[7], bfhi_(p.w), acc);
  return acc;
}

// ===================== init =====================
__global__ void __launch_bounds__(256) kInit(float* ws){
  int g = blockIdx.x*256 + threadIdx.x;          // 65536 threads
  int* fl = (int*)(ws + O_FLG);
  if (g < 768) fl[g] = (g < 256 && (g & 15) == 0) ? 1 : 0;   // hflag=1 (h(0) via kPre)
  for (int i=g;i<262144;i+=65536) ws[O_M+i]=1e-6f;
  for (int i=g;i<1048576;i+=65536) ws[O_L+i]=0.f;
}

// ===================== kConv: pack + transpose weights to bf16 pairs =============
__global__ void __launch_bounds__(256)
kConv(const float* __restrict__ W_hid, const float* __restrict__ W_iface,
      const float* __restrict__ W_out, const float* __restrict__ W_memout,
      float* __restrict__ ws)
{
  unsigned* Wip = (unsigned*)(ws + O_WIP);
  unsigned* Whp = (unsigned*)(ws + O_WHP);
  unsigned* Wop = (unsigned*)(ws + O_WOP);
  unsigned* Wmp = (unsigned*)(ws + O_WMP);
  int g = blockIdx.x*256 + threadIdx.x;          // 65536 threads
  for (int i = g; i < 471*256; i += 65536) {
    int c = i >> 8, kp = i & 255;
    Wip[c*WIPS + kp] = bf16pack_(W_iface[(size_t)(2*kp)*IFACE_N + c],
                                 W_iface[(size_t)(2*kp+1)*IFACE_N + c]);
  }
  {
    int c = g >> 7, kp = g & 127;
    Whp[c*WHPS + kp] = bf16pack_(W_hid[(size_t)(512 + 2*kp)*512 + c],
                                 W_hid[(size_t)(513 + 2*kp)*512 + c]);
  }
  for (int i = g; i < 512*256; i += 65536) {
    int c = i >> 8, kp = i & 255;
    Wop[c*WOPS + kp] = bf16pack_(W_out[(size_t)(2*kp)*512 + c],
                                 W_out[(size_t)(2*kp+1)*512 + c]);
  }
  {
    int c = g >> 7, kp = g & 127;
    Wmp[c*WMPS + kp] = bf16pack_(W_memout[(size_t)(2*kp)*512 + c],
                                 W_memout[(size_t)(2*kp+1)*512 + c]);
  }
}

// ===================== kPre: hx = x @ W_hid[0:512] + b ; h(0) =====================
__global__ void __launch_bounds__(256)
kPre(const float* __restrict__ x, const float* __restrict__ W_hid,
     const float* __restrict__ b_hid, float* __restrict__ ws)
{
  const int tid = threadIdx.x, blk = blockIdx.x;
  const int r0 = (blk >> 1) * 8, col = (blk & 1) * 256 + tid;
  __shared__ float xs[8][512];
  for (int i = tid; i < 8*512; i += 256) {
    int rr = i >> 9, k = i & 511;
    xs[rr][k] = x[(size_t)(r0+rr)*512 + k];
  }
  __syncthreads();
  float a0=0,a1=0,a2=0,a3=0,a4=0,a5=0,a6=0,a7=0;
  const float* Wp = W_hid + col;
#pragma unroll 4
  for (int k = 0; k < 512; k++) {
    float w = Wp[(size_t)k*512];
    a0 = fmaf(xs[0][k], w, a0); a1 = fmaf(xs[1][k], w, a1);
    a2 = fmaf(xs[2][k], w, a2); a3 = fmaf(xs[3][k], w, a3);
    a4 = fmaf(xs[4][k], w, a4); a5 = fmaf(xs[5][k], w, a5);
    a6 = fmaf(xs[6][k], w, a6); a7 = fmaf(xs[7][k], w, a7);
  }
  float bh = b_hid[col];
  float av[8] = {a0,a1,a2,a3,a4,a5,a6,a7};
#pragma unroll
  for (int i = 0; i < 8; i++) {
    int r = r0 + i;
    float v = av[i] + bh;
    ws[O_HX + (size_t)r*512 + col] = v;
    if (r < 16) ws[O_H + r*512 + col] = fmaxf(v, 0.f);   // h(0), slot 0
  }
}

// ===================== kRun: persistent, 16 batch + 16 out-helper blocks ==========
__global__ void __launch_bounds__(1024, 4)
kRun(const unsigned* __restrict__ WipT, const unsigned* __restrict__ WhpT,
     const unsigned* __restrict__ WopT, const unsigned* __restrict__ WmpT,
     const float* __restrict__ hx, float* __restrict__ Mall,
     float* __restrict__ Lall, float* __restrict__ ws, float* __restrict__ out)
{
  const int tid = threadIdx.x, blk = blockIdx.x;
  const int wv = tid >> 6, lane = tid & 63;
  int* fl = (int*)(ws + O_FLG);

  __shared__ float hl[512];
  __shared__ float ifcl[480];
  __shared__ float psum[1024];
  __shared__ float ul[256], pOl[256], pNl[256], wwl[256];
  __shared__ float rwl[1024];
  __shared__ float wkn[64], rknl[256];
  __shared__ alignas(16) float evl[64], wvl[64];
  __shared__ float ssorted[256];
  __shared__ int   sidx[256];
  __shared__ float sal[256], siml[256];
  __shared__ float fwdl[1024], bwdl[1024], rcs[1024];
  __shared__ alignas(16) float bb[16][260];
  __shared__ float rvl[256];

  if (blk >= 16) {
    // ================= out-helper: out(t) = h(t)@W_out + rv(t)@W_memout =====
    const int b = blk - 16;
    int* hfl = fl + b*16; int* rfl = fl + 256 + b*16; int* ofl = fl + 512 + b*16;
    for (int t = 0; t < TS; t++) {
      if (tid == 0) { waitge_(hfl, t+1); waitge_(rfl, t+1); }
      __syncthreads();
      if (tid < 512)      hl[tid] = ws[O_H + (t&1)*8192 + b*512 + tid];
      else if (tid < 768) rvl[tid-512] = ws[O_RV + (t&1)*4096 + b*256 + (tid-512)];
      __syncthreads();
      int col = tid & 511, kseg = tid >> 9;
      const uint4* Wo = (const uint4*)(WopT + col*WOPS + kseg*128);
      const float* hp = hl + kseg*256;
      float acc = 0.f;
#pragma unroll 8
      for (int q4 = 0; q4 < 32; q4++) acc = dot8_(Wo[q4], hp + q4*8, acc);
      const uint4* Wm = (const uint4*)(WmpT + col*WMPS + kseg*64);
      const float* rp = rvl + kseg*128;
#pragma unroll 8
      for (int q4 = 0; q4 < 16; q4++) acc = dot8_(Wm[q4], rp + q4*8, acc);
      psum[tid] = acc;
      __syncthreads();
      if (tid < 512) out[(size_t)t*8192 + b*512 + tid] = psum[tid] + psum[512+tid];
      __syncthreads();
      if (tid == 0) publish_(ofl, t+1);
    }
    return;
  }

  // ================= batch block =================
  const int b = blk;
  float* Mg = Mall + (size_t)b*16384;
  float* Lg = Lall + (size_t)b*65536;
  int* ofl = fl + 512 + b*16;
  int* hfl = fl + b*16; int* rfl = fl + 256 + b*16;

  if (tid < 512) hl[tid] = ws[O_H + b*512 + tid];     // h(0), slot 0
  rwl[tid] = 0.f;
  if (tid < 256){ ul[tid]=0.f; pOl[tid]=0.f; wwl[tid]=0.f; }
  __syncthreads();

  for (int t = 0; t < TS; t++) {
    // ---- iface = h @ W_iface (bf16 uint4, k-split 2) ----
    {
      int col = tid & 511, kseg = tid >> 9;
      float acc = 0.f;
      if (col < IFACE_N) {
        const uint4* Wp = (const uint4*)(WipT + col*WIPS + kseg*128);
        const float* hp = hl + kseg*256;
#pragma unroll 8
        for (int q4 = 0; q4 < 32; q4++) acc = dot8_(Wp[q4], hp + q4*8, acc);
      }
      psum[tid] = acc;
    }
    __syncthreads();
    if (tid < IFACE_N) ifcl[tid] = psum[tid] + psum[512+tid];
    __syncthreads();

    // ---- usage update + key norms + gate vectors ----
    if (tid < 256) {
      float ret = 1.f;
#pragma unroll
      for (int r = 0; r < 4; r++) {
        float fg = sigmoidf_(ifcl[OFF_FG + r]);
        ret *= (1.f - fg * rwl[r*256 + tid]);
      }
      float uo = ul[tid], wo = wwl[tid];
      ul[tid] = (uo + wo - uo*wo) * ret;
    } else if (tid >= 448 && tid < 512) {              // wave 7: wk norm
      float kv = ifcl[OFF_WK + lane];
      float ss = wsum_(kv*kv);
      wkn[lane] = kv / (sqrtf(ss) + EPS_);
    } else if (tid >= 512 && tid < 768) {              // waves 8..11: rk norms
      int r = wv - 8;
      float kv = ifcl[OFF_RK + r*64 + lane];
      float ss = wsum_(kv*kv);
      rknl[r*64 + lane] = kv / (sqrtf(ss) + EPS_);
    } else if (tid >= 768 && tid < 832) {              // wave 12: erase vec
      evl[lane] = sigmoidf_(ifcl[OFF_EV + lane]);
    } else if (tid >= 832 && tid < 896) {              // wave 13: write vec
      wvl[lane] = ifcl[OFF_WV + lane];
    }
    __syncthreads();

    // ---- stable rank argsort + cumprod alloc ----
    {
      int n = tid >> 2, q = tid & 3;
      float un = ul[n];
      const float* sp = ul + q*64;
      int cnt = 0;
#pragma unroll 8
      for (int m = 0; m < 64; m++) {
        float um = sp[m];
        int gm = q*64 + m;
        cnt += (um < un || (um == un && gm < n)) ? 1 : 0;
      }
      cnt += __shfl_xor(cnt, 1, 64);
      cnt += __shfl_xor(cnt, 2, 64);
      if (q == 0) { ssorted[cnt] = un; sidx[cnt] = n; }
    }
    __syncthreads();
    if (wv == 0) {
      float carry = 1.f;
#pragma unroll
      for (int c2 = 0; c2 < 4; c2++) {
        float v0 = ssorted[c2*64 + lane];
        float v = v0;
#pragma unroll
        for (int off = 1; off < 64; off <<= 1) {
          float uu = __shfl_up(v, off, 64);
          if (lane >= off) v *= uu;
        }
        float e = __shfl_up(v, 1, 64);
        if (lane == 0) e = 1.f;
        sal[sidx[c2*64 + lane]] = (1.f - v0) * e * carry;
        carry *= __shfl(v, 63, 64);
      }
    }
    __syncthreads();

    // ---- write content weights over OLD M ----
    {
      int n = tid >> 2, q = tid & 3;
      const float4* Mp = (const float4*)(Mg + n*64 + q*16);
      float ss = 0.f, dt = 0.f;
#pragma unroll
      for (int i = 0; i < 4; i++) {
        float4 mv = Mp[i];
        const float* kp = wkn + q*16 + i*4;
        ss += mv.x*mv.x + mv.y*mv.y + mv.z*mv.z + mv.w*mv.w;
        dt += mv.x*kp[0] + mv.y*kp[1] + mv.z*kp[2] + mv.w*kp[3];
      }
      ss += __shfl_xor(ss,1,64); ss += __shfl_xor(ss,2,64);
      dt += __shfl_xor(dt,1,64); dt += __shfl_xor(dt,2,64);
      if (q == 0) {
        float wb = oneplusf_(ifcl[OFF_WB]);
        siml[n] = wb * dt / (sqrtf(ss) + EPS_);
      }
    }
    __syncthreads();
    if (tid < 256) {
      float v0 = siml[lane], v1 = siml[64+lane], v2 = siml[128+lane], v3 = siml[192+lane];
      float mx = wmax_(fmaxf(fmaxf(v0,v1), fmaxf(v2,v3)));
      float ssum = wsum_(expf(v0-mx)+expf(v1-mx)+expf(v2-mx)+expf(v3-mx));
      float cw = expf(siml[tid]-mx) / ssum;
      float ag = sigmoidf_(ifcl[OFF_AG]);
      float wg = sigmoidf_(ifcl[OFF_WG]);
      wwl[tid] = wg * (ag*sal[tid] + (1.f-ag)*cw);
      ssorted[tid] = wwl[tid];
    }
    __syncthreads();
    if (tid < 256) {
      float s4 = ssorted[lane] + ssorted[64+lane] + ssorted[128+lane] + ssorted[192+lane];
      float wws = wsum_(s4);
      pNl[tid] = (1.f - wws)*pOl[tid] + wwl[tid];
    }
    __syncthreads();

    // ---- L update + fwd + bwd ----
    {
      int j0 = lane*4;
      float wwj0 = wwl[j0], wwj1 = wwl[j0+1], wwj2 = wwl[j0+2], wwj3 = wwl[j0+3];
      float pj0 = pOl[j0], pj1 = pOl[j0+1], pj2 = pOl[j0+2], pj3 = pOl[j0+3];
      float rw00 = rwl[j0],     rw01 = rwl[j0+1],     rw02 = rwl[j0+2],     rw03 = rwl[j0+3];
      float rw10 = rwl[256+j0], rw11 = rwl[256+j0+1], rw12 = rwl[256+j0+2], rw13 = rwl[256+j0+3];
      float rw20 = rwl[512+j0], rw21 = rwl[512+j0+1], rw22 = rwl[512+j0+2], rw23 = rwl[512+j0+3];
      float rw30 = rwl[768+j0], rw31 = rwl[768+j0+1], rw32 = rwl[768+j0+2], rw33 = rwl[768+j0+3];
      float4 ba0 = {0,0,0,0}, ba1 = {0,0,0,0}, ba2 = {0,0,0,0}, ba3 = {0,0,0,0};
      float4* Lrow = (float4*)Lg;
#pragma unroll 4
      for (int ii = 0; ii < 16; ii++) {
        int i = wv*16 + ii;
        float wwi = wwl[i];
        float4 lv = Lrow[i*64 + lane];
        float4 nv;
        nv.x = (1.f - wwi - wwj0)*lv.x + wwi*pj0;
        nv.y = (1.f - wwi - wwj1)*lv.y + wwi*pj1;
        nv.z = (1.f - wwi - wwj2)*lv.z + wwi*pj2;
        nv.w = (1.f - wwi - wwj3)*lv.w + wwi*pj3;
        if (j0   == i) nv.x = 0.f;
        if (j0+1 == i) nv.y = 0.f;
        if (j0+2 == i) nv.z = 0.f;
        if (j0+3 == i) nv.w = 0.f;
        Lrow[i*64 + lane] = nv;
        float f0 = nv.x*rw00 + nv.y*rw01 + nv.z*rw02 + nv.w*rw03;
        float f1 = nv.x*rw10 + nv.y*rw11 + nv.z*rw12 + nv.w*rw13;
        float f2 = nv.x*rw20 + nv.y*rw21 + nv.z*rw22 + nv.w*rw23;
        float f3 = nv.x*rw30 + nv.y*rw31 + nv.z*rw32 + nv.w*rw33;
        f0 = wsum_(f0); f1 = wsum_(f1); f2 = wsum_(f2); f3 = wsum_(f3);
        if (lane == 0) { fwdl[i] = f0; fwdl[256+i] = f1; fwdl[512+i] = f2; fwdl[768+i] = f3; }
        float ri0 = rwl[i], ri1 = rwl[256+i], ri2 = rwl[512+i], ri3 = rwl[768+i];
        ba0.x = fmaf(ri0, nv.x, ba0.x); ba0.y = fmaf(ri0, nv.y, ba0.y);
        ba0.z = fmaf(ri0, nv.z, ba0.z); ba0.w = fmaf(ri0, nv.w, ba0.w);
        ba1.x = fmaf(ri1, nv.x, ba1.x); ba1.y = fmaf(ri1, nv.y, ba1.y);
        ba1.z = fmaf(ri1, nv.z, ba1.z); ba1.w = fmaf(ri1, nv.w, ba1.w);
        ba2.x = fmaf(ri2, nv.x, ba2.x); ba2.y = fmaf(ri2, nv.y, ba2.y);
        ba2.z = fmaf(ri2, nv.z, ba2.z); ba2.w = fmaf(ri2, nv.w, ba2.w);
        ba3.x = fmaf(ri3, nv.x, ba3.x); ba3.y = fmaf(ri3, nv.y, ba3.y);
        ba3.z = fmaf(ri3, nv.z, ba3.z); ba3.w = fmaf(ri3, nv.w, ba3.w);
      }
#pragma unroll
      for (int r = 0; r < 4; r++) {
        float4 v = (r==0) ? ba0 : (r==1) ? ba1 : (r==2) ? ba2 : ba3;
        *(float4*)&bb[wv][j0] = v;
        __syncthreads();
        if (tid < 256) {
          float s = 0.f;
#pragma unroll
          for (int w2 = 0; w2 < 16; w2++) s += bb[w2][tid];
          bwdl[r*256 + tid] = s;
        }
        __syncthreads();
      }
    }
    if (tid < 256) pOl[tid] = pNl[tid];   // p for next step (L-update done)

    // ---- M update + rc logits (NEW M) ----
    {
      int n = tid >> 2, q = tid & 3;
      float wwn = wwl[n];
      float4* Mp = (float4*)(Mg + n*64 + q*16);
      float ss = 0.f, d0 = 0.f, d1 = 0.f, d2 = 0.f, d3 = 0.f;
#pragma unroll
      for (int i = 0; i < 4; i++) {
        float4 mv = Mp[i];
        int w0 = q*16 + i*4;
        float4 ev = *(const float4*)(evl + w0);
        float4 wq = *(const float4*)(wvl + w0);
        float4 nv;
        nv.x = mv.x*(1.f - wwn*ev.x) + wwn*wq.x;
        nv.y = mv.y*(1.f - wwn*ev.y) + wwn*wq.y;
        nv.z = mv.z*(1.f - wwn*ev.z) + wwn*wq.z;
        nv.w = mv.w*(1.f - wwn*ev.w) + wwn*wq.w;
        Mp[i] = nv;
        ss += nv.x*nv.x + nv.y*nv.y + nv.z*nv.z + nv.w*nv.w;
        const float* k0 = rknl + w0;
        const float* k1 = rknl + 64 + w0;
        const float* k2 = rknl + 128 + w0;
        const float* k3 = rknl + 192 + w0;
        d0 += nv.x*k0[0] + nv.y*k0[1] + nv.z*k0[2] + nv.w*k0[3];
        d1 += nv.x*k1[0] + nv.y*k1[1] + nv.z*k1[2] + nv.w*k1[3];
        d2 += nv.x*k2[0] + nv.y*k2[1] + nv.z*k2[2] + nv.w*k2[3];
        d3 += nv.x*k3[0] + nv.y*k3[1] + nv.z*k3[2] + nv.w*k3[3];
      }
      ss += __shfl_xor(ss,1,64); ss += __shfl_xor(ss,2,64);
      d0 += __shfl_xor(d0,1,64); d0 += __shfl_xor(d0,2,64);
      d1 += __shfl_xor(d1,1,64); d1 += __shfl_xor(d1,2,64);
      d2 += __shfl_xor(d2,1,64); d2 += __shfl_xor(d2,2,64);
      d3 += __shfl_xor(d3,1,64); d3 += __shfl_xor(d3,2,64);
      if (q == 0) {
        float inv = 1.f/(sqrtf(ss) + EPS_);
        rcs[n]     = oneplusf_(ifcl[OFF_RB+0]) * d0 * inv;
        rcs[256+n] = oneplusf_(ifcl[OFF_RB+1]) * d1 * inv;
        rcs[512+n] = oneplusf_(ifcl[OFF_RB+2]) * d2 * inv;
        rcs[768+n] = oneplusf_(ifcl[OFF_RB+3]) * d3 * inv;
      }
    }
    __syncthreads();

    // ---- rc softmax ----
    if (wv < 4) {
      float* rp = rcs + wv*256;
      float v0 = rp[lane], v1 = rp[64+lane], v2 = rp[128+lane], v3 = rp[192+lane];
      float mx = wmax_(fmaxf(fmaxf(v0,v1), fmaxf(v2,v3)));
      float e0 = expf(v0-mx), e1 = expf(v1-mx), e2 = expf(v2-mx), e3 = expf(v3-mx);
      float inv = 1.f / wsum_(e0+e1+e2+e3);
      rp[lane] = e0*inv; rp[64+lane] = e1*inv; rp[128+lane] = e2*inv; rp[192+lane] = e3*inv;
    }
    __syncthreads();

    // ---- rw_new ----
    {
      int r = tid >> 8;
      float e0 = ifcl[OFF_RM + r*3+0], e1 = ifcl[OFF_RM + r*3+1], e2 = ifcl[OFF_RM + r*3+2];
      float mx = fmaxf(e0, fmaxf(e1, e2));
      float x0 = expf(e0-mx), x1 = expf(e1-mx), x2 = expf(e2-mx);
      float inv = 1.f/(x0+x1+x2);
      rwl[tid] = (x0*bwdl[tid] + x1*rcs[tid] + x2*fwdl[tid]) * inv;
    }
    __syncthreads();

    // ---- rv_new ----
    {
      int w = tid & 63, r = (tid >> 6) & 3, c = tid >> 8;
      const float* rp = rwl + r*256 + c*64;
      float acc = 0.f;
#pragma unroll 8
      for (int n = 0; n < 64; n++) acc = fmaf(Mg[(c*64+n)*64 + w], rp[n], acc);
      psum[c*256 + r*64 + w] = acc;
    }
    __syncthreads();
    if (tid < 256)
      rvl[tid] = psum[tid] + psum[256+tid] + psum[512+tid] + psum[768+tid];

    // ---- publish rv(t) (slot t&1; prior occupant rv(t-2) consumed by out(t-2)) ----
    if (tid == 0) waitge_(ofl, t-1);
    __syncthreads();
    if (tid < 256) ws[O_RV + (t&1)*4096 + b*256 + tid] = rvl[tid];
    __syncthreads();
    if (tid == 0) publish_(rfl, t+1);

    // ---- h(t+1) = relu(hx(t+1) + rv @ W_hid[512:768] bf16 uint4) ----
    if (t + 1 < TS) {
      if (tid == 0) waitge_(ofl, t);   // slot (t+1)&1 held h(t-1), consumed by out(t-1)
      __syncthreads();
      int col = tid & 511, kseg = tid >> 9;
      const uint4* Wp = (const uint4*)(WhpT + col*WHPS + kseg*64);
      const float* rp = rvl + kseg*128;
      float acc = 0.f;
#pragma unroll 8
      for (int q4 = 0; q4 < 16; q4++) acc = dot8_(Wp[q4], rp + q4*8, acc);
      psum[tid] = acc;
      __syncthreads();
      if (tid < 512) {
        float v = hx[(size_t)((t+1)*16 + b)*512 + tid] + psum[tid] + psum[512+tid];
        v = fmaxf(v, 0.f);
        hl[tid] = v;
        ws[O_H + ((t+1)&1)*8192 + b*512 + tid] = v;
      }
      __syncthreads();
      if (tid == 0) publish_(hfl, t+2);
    }
  }
}

extern "C" void kernel_launch(void* const* d_in, const int* in_sizes, int n_in,
                              void* d_out, int out_size, void* d_ws, size_t ws_size,
                              hipStream_t stream) {
  (void)in_sizes; (void)n_in; (void)out_size; (void)ws_size;
  const float* x        = (const float*)d_in[0];
  const float* W_hid    = (const float*)d_in[1];
  const float* b_hid    = (const float*)d_in[2];
  const float* W_iface  = (const float*)d_in[3];
  const float* W_out    = (const float*)d_in[4];
  const float* W_memout = (const float*)d_in[5];
  float* outp = (float*)d_out;
  float* ws   = (float*)d_ws;

  hipLaunchKernelGGL(kInit, dim3(256), dim3(256), 0, stream, ws);
  hipLaunchKernelGGL(kConv, dim3(256), dim3(256), 0, stream,
                     W_hid, W_iface, W_out, W_memout, ws);
  hipLaunchKernelGGL(kPre,  dim3(256), dim3(256), 0, stream, x, W_hid, b_hid, ws);
  const unsigned* WipT = (const unsigned*)(ws + O_WIP);
  const unsigned* WhpT = (const unsigned*)(ws + O_WHP);
  const unsigned* WopT = (const unsigned*)(ws + O_WOP);
  const unsigned* WmpT = (const unsigned*)(ws + O_WMP);
  const float* hx = ws + O_HX;
  float* Mall = ws + O_M;
  float* Lall = ws + O_L;
  void* args[] = {&WipT, &WhpT, &WopT, &WmpT, &hx, &Mall, &Lall, &ws, &outp};
  hipLaunchCooperativeKernel((void*)kRun, dim3(32), dim3(1024), args, 0, stream);
}

// Round 11
// 3498.841 us; speedup vs baseline: 1.5421x; 1.2218x over previous
//
#include <hip/hip_runtime.h>
#include <math.h>

#define TS 64
#define IFACE_N 471
#define EPS_ 1e-6f

// iface column offsets
#define OFF_RK 0
#define OFF_RB 256
#define OFF_WK 260
#define OFF_WB 324
#define OFF_EV 325
#define OFF_WV 389
#define OFF_FG 453
#define OFF_AG 457
#define OFF_WG 458
#define OFF_RM 459

// ws float offsets
#define O_HX   0         // 524288 : hx[t*16+b][512]; overwritten in-place with h(t)
#define O_RS   524288    // 262144 : rv(t) save (t*16+b)x256
#define O_M    786432    // 262144
#define O_L    1048576   // 1048576
// packed bf16 weights, transposed [col][kpair], padded strides:
#define WIPS 260
#define WHPS 132
#define O_WIP  2097152   // 471*260 = 122460 uints   W_iface (256 kp)
#define O_WHP  2219612   // 512*132 = 67584          W_hid[512:768] (128 kp)
// total 2,287,196 floats = 9.15 MB

__device__ __forceinline__ float sigmoidf_(float x){ return 1.f/(1.f+expf(-x)); }
__device__ __forceinline__ float oneplusf_(float x){ return 1.f+fmaxf(x,0.f)+log1pf(expf(-fabsf(x))); }
__device__ __forceinline__ float wsum_(float v){
#pragma unroll
  for(int off=32; off>0; off>>=1) v += __shfl_xor(v,off,64);
  return v;
}
__device__ __forceinline__ float wmax_(float v){
#pragma unroll
  for(int off=32; off>0; off>>=1) v = fmaxf(v,__shfl_xor(v,off,64));
  return v;
}
__device__ __forceinline__ unsigned bf16rne_(float f){
  unsigned u = __float_as_uint(f);
  return (u + 0x7FFFu + ((u >> 16) & 1u)) >> 16;
}
__device__ __forceinline__ unsigned bf16pack_(float lo, float hi){
  return bf16rne_(lo) | (bf16rne_(hi) << 16);
}
__device__ __forceinline__ float bflo_(unsigned p){ return __uint_as_float(p << 16); }
__device__ __forceinline__ float bfhi_(unsigned p){ return __uint_as_float(p & 0xFFFF0000u); }

__device__ __forceinline__ float dot8_(uint4 p, const float* a, float acc){
  acc = fmaf(a[0], bflo_(p.x), acc); acc = fmaf(a[1], bfhi_(p.x), acc);
  acc = fmaf(a[2], bflo_(p.y), acc); acc = fmaf(a[3], bfhi_(p.y), acc);
  acc = fmaf(a[4], bflo_(p.z), acc); acc = fmaf(a[5], bfhi_(p.z), acc);
  acc = fmaf(a[6], bflo_(p.w), acc); acc = fmaf(a[7], bfhi_(p.w), acc);
  return acc;
}

// ===================== init =====================
__global__ void __launch_bounds__(256) kInit(float* ws){
  int g = blockIdx.x*256 + threadIdx.x;          // 65536 threads
  for (int i=g;i<262144;i+=65536) ws[O_M+i]=1e-6f;
  for (int i=g;i<1048576;i+=65536) ws[O_L+i]=0.f;
}

// ===================== kConv: pack + transpose recurrent-path weights =============
__global__ void __launch_bounds__(256)
kConv(const float* __restrict__ W_hid, const float* __restrict__ W_iface,
      float* __restrict__ ws)
{
  unsigned* Wip = (unsigned*)(ws + O_WIP);
  unsigned* Whp = (unsigned*)(ws + O_WHP);
  int g = blockIdx.x*256 + threadIdx.x;          // 65536 threads
  for (int i = g; i < 471*256; i += 65536) {
    int c = i >> 8, kp = i & 255;
    Wip[c*WIPS + kp] = bf16pack_(W_iface[(size_t)(2*kp)*IFACE_N + c],
                                 W_iface[(size_t)(2*kp+1)*IFACE_N + c]);
  }
  {
    int c = g >> 7, kp = g & 127;
    Whp[c*WHPS + kp] = bf16pack_(W_hid[(size_t)(512 + 2*kp)*512 + c],
                                 W_hid[(size_t)(513 + 2*kp)*512 + c]);
  }
}

// ===================== kPre: hx = x @ W_hid[0:512] + b =====================
__global__ void __launch_bounds__(256)
kPre(const float* __restrict__ x, const float* __restrict__ W_hid,
     const float* __restrict__ b_hid, float* __restrict__ ws)
{
  const int tid = threadIdx.x, blk = blockIdx.x;
  const int r0 = (blk >> 1) * 8, col = (blk & 1) * 256 + tid;
  __shared__ float xs[8][512];
  for (int i = tid; i < 8*512; i += 256) {
    int rr = i >> 9, k = i & 511;
    xs[rr][k] = x[(size_t)(r0+rr)*512 + k];
  }
  __syncthreads();
  float a0=0,a1=0,a2=0,a3=0,a4=0,a5=0,a6=0,a7=0;
  const float* Wp = W_hid + col;
#pragma unroll 4
  for (int k = 0; k < 512; k++) {
    float w = Wp[(size_t)k*512];
    a0 = fmaf(xs[0][k], w, a0); a1 = fmaf(xs[1][k], w, a1);
    a2 = fmaf(xs[2][k], w, a2); a3 = fmaf(xs[3][k], w, a3);
    a4 = fmaf(xs[4][k], w, a4); a5 = fmaf(xs[5][k], w, a5);
    a6 = fmaf(xs[6][k], w, a6); a7 = fmaf(xs[7][k], w, a7);
  }
  float bh = b_hid[col];
  float av[8] = {a0,a1,a2,a3,a4,a5,a6,a7};
#pragma unroll
  for (int i = 0; i < 8; i++)
    ws[O_HX + (size_t)(r0+i)*512 + col] = av[i] + bh;
}

// ===================== kLoop: 16 independent per-batch blocks, all 64 steps =======
__global__ void __launch_bounds__(1024, 4)
kLoop(const unsigned* __restrict__ WipT, const unsigned* __restrict__ WhpT,
      float* __restrict__ hx, float* __restrict__ rvs,
      float* __restrict__ Mall, float* __restrict__ Lall)
{
  const int tid = threadIdx.x, b = blockIdx.x;
  const int wv = tid >> 6, lane = tid & 63;

  __shared__ float hl[512];
  __shared__ float ifcl[480];
  __shared__ float psum[1024];
  __shared__ float ul[256], pOl[256], pNl[256], wwl[256];
  __shared__ float rwl[1024];
  __shared__ float wkn[64], rknl[256];
  __shared__ alignas(16) float evl[64], wvl[64];
  __shared__ float ssorted[256];
  __shared__ int   sidx[256];
  __shared__ float sal[256], siml[256];
  __shared__ float fwdl[1024], bwdl[1024], rcs[1024];
  __shared__ alignas(16) float bb[16][260];
  __shared__ float rvl[256];

  float* Mg = Mall + (size_t)b*16384;
  float* Lg = Lall + (size_t)b*65536;

  if (tid < 512) hl[tid] = fmaxf(hx[(size_t)b*512 + tid], 0.f);   // h(0)
  rwl[tid] = 0.f;
  if (tid < 256){ ul[tid]=0.f; pOl[tid]=0.f; wwl[tid]=0.f; }
  __syncthreads();

  for (int t = 0; t < TS; t++) {
    // ---- save h(t) for the deferred output GEMM (overwrites consumed hx[t]) ----
    if (tid < 512) hx[(size_t)(t*16 + b)*512 + tid] = hl[tid];

    // ---- iface = h @ W_iface (bf16 uint4, k-split 2) ----
    {
      int col = tid & 511, kseg = tid >> 9;
      float acc = 0.f;
      if (col < IFACE_N) {
        const uint4* Wp = (const uint4*)(WipT + col*WIPS + kseg*128);
        const float* hp = hl + kseg*256;
#pragma unroll 8
        for (int q4 = 0; q4 < 32; q4++) acc = dot8_(Wp[q4], hp + q4*8, acc);
      }
      psum[tid] = acc;
    }
    __syncthreads();
    if (tid < IFACE_N) ifcl[tid] = psum[tid] + psum[512+tid];
    __syncthreads();

    // ---- usage update + key norms + gate vectors ----
    if (tid < 256) {
      float ret = 1.f;
#pragma unroll
      for (int r = 0; r < 4; r++) {
        float fg = sigmoidf_(ifcl[OFF_FG + r]);
        ret *= (1.f - fg * rwl[r*256 + tid]);
      }
      float uo = ul[tid], wo = wwl[tid];
      ul[tid] = (uo + wo - uo*wo) * ret;
    } else if (tid >= 448 && tid < 512) {              // wave 7: wk norm
      float kv = ifcl[OFF_WK + lane];
      float ss = wsum_(kv*kv);
      wkn[lane] = kv / (sqrtf(ss) + EPS_);
    } else if (tid >= 512 && tid < 768) {              // waves 8..11: rk norms
      int r = wv - 8;
      float kv = ifcl[OFF_RK + r*64 + lane];
      float ss = wsum_(kv*kv);
      rknl[r*64 + lane] = kv / (sqrtf(ss) + EPS_);
    } else if (tid >= 768 && tid < 832) {              // wave 12: erase vec
      evl[lane] = sigmoidf_(ifcl[OFF_EV + lane]);
    } else if (tid >= 832 && tid < 896) {              // wave 13: write vec
      wvl[lane] = ifcl[OFF_WV + lane];
    }
    __syncthreads();

    // ---- stable rank argsort + cumprod alloc ----
    {
      int n = tid >> 2, q = tid & 3;
      float un = ul[n];
      const float* sp = ul + q*64;
      int cnt = 0;
#pragma unroll 8
      for (int m = 0; m < 64; m++) {
        float um = sp[m];
        int gm = q*64 + m;
        cnt += (um < un || (um == un && gm < n)) ? 1 : 0;
      }
      cnt += __shfl_xor(cnt, 1, 64);
      cnt += __shfl_xor(cnt, 2, 64);
      if (q == 0) { ssorted[cnt] = un; sidx[cnt] = n; }
    }
    __syncthreads();
    if (wv == 0) {
      float carry = 1.f;
#pragma unroll
      for (int c2 = 0; c2 < 4; c2++) {
        float v0 = ssorted[c2*64 + lane];
        float v = v0;
#pragma unroll
        for (int off = 1; off < 64; off <<= 1) {
          float uu = __shfl_up(v, off, 64);
          if (lane >= off) v *= uu;
        }
        float e = __shfl_up(v, 1, 64);
        if (lane == 0) e = 1.f;
        sal[sidx[c2*64 + lane]] = (1.f - v0) * e * carry;
        carry *= __shfl(v, 63, 64);
      }
    }
    __syncthreads();

    // ---- write content weights over OLD M ----
    {
      int n = tid >> 2, q = tid & 3;
      const float4* Mp = (const float4*)(Mg + n*64 + q*16);
      float ss = 0.f, dt = 0.f;
#pragma unroll
      for (int i = 0; i < 4; i++) {
        float4 mv = Mp[i];
        const float* kp = wkn + q*16 + i*4;
        ss += mv.x*mv.x + mv.y*mv.y + mv.z*mv.z + mv.w*mv.w;
        dt += mv.x*kp[0] + mv.y*kp[1] + mv.z*kp[2] + mv.w*kp[3];
      }
      ss += __shfl_xor(ss,1,64); ss += __shfl_xor(ss,2,64);
      dt += __shfl_xor(dt,1,64); dt += __shfl_xor(dt,2,64);
      if (q == 0) {
        float wb = oneplusf_(ifcl[OFF_WB]);
        siml[n] = wb * dt / (sqrtf(ss) + EPS_);
      }
    }
    __syncthreads();
    if (tid < 256) {
      float v0 = siml[lane], v1 = siml[64+lane], v2 = siml[128+lane], v3 = siml[192+lane];
      float mx = wmax_(fmaxf(fmaxf(v0,v1), fmaxf(v2,v3)));
      float ssum = wsum_(expf(v0-mx)+expf(v1-mx)+expf(v2-mx)+expf(v3-mx));
      float cw = expf(siml[tid]-mx) / ssum;
      float ag = sigmoidf_(ifcl[OFF_AG]);
      float wg = sigmoidf_(ifcl[OFF_WG]);
      wwl[tid] = wg * (ag*sal[tid] + (1.f-ag)*cw);
      ssorted[tid] = wwl[tid];
    }
    __syncthreads();
    if (tid < 256) {
      float s4 = ssorted[lane] + ssorted[64+lane] + ssorted[128+lane] + ssorted[192+lane];
      float wws = wsum_(s4);
      pNl[tid] = (1.f - wws)*pOl[tid] + wwl[tid];
    }
    __syncthreads();

    // ---- L update + fwd + bwd ----
    {
      int j0 = lane*4;
      float wwj0 = wwl[j0], wwj1 = wwl[j0+1], wwj2 = wwl[j0+2], wwj3 = wwl[j0+3];
      float pj0 = pOl[j0], pj1 = pOl[j0+1], pj2 = pOl[j0+2], pj3 = pOl[j0+3];
      float rw00 = rwl[j0],     rw01 = rwl[j0+1],     rw02 = rwl[j0+2],     rw03 = rwl[j0+3];
      float rw10 = rwl[256+j0], rw11 = rwl[256+j0+1], rw12 = rwl[256+j0+2], rw13 = rwl[256+j0+3];
      float rw20 = rwl[512+j0], rw21 = rwl[512+j0+1], rw22 = rwl[512+j0+2], rw23 = rwl[512+j0+3];
      float rw30 = rwl[768+j0], rw31 = rwl[768+j0+1], rw32 = rwl[768+j0+2], rw33 = rwl[768+j0+3];
      float4 ba0 = {0,0,0,0}, ba1 = {0,0,0,0}, ba2 = {0,0,0,0}, ba3 = {0,0,0,0};
      float4* Lrow = (float4*)Lg;
#pragma unroll 4
      for (int ii = 0; ii < 16; ii++) {
        int i = wv*16 + ii;
        float wwi = wwl[i];
        float4 lv = Lrow[i*64 + lane];
        float4 nv;
        nv.x = (1.f - wwi - wwj0)*lv.x + wwi*pj0;
        nv.y = (1.f - wwi - wwj1)*lv.y + wwi*pj1;
        nv.z = (1.f - wwi - wwj2)*lv.z + wwi*pj2;
        nv.w = (1.f - wwi - wwj3)*lv.w + wwi*pj3;
        if (j0   == i) nv.x = 0.f;
        if (j0+1 == i) nv.y = 0.f;
        if (j0+2 == i) nv.z = 0.f;
        if (j0+3 == i) nv.w = 0.f;
        Lrow[i*64 + lane] = nv;
        float f0 = nv.x*rw00 + nv.y*rw01 + nv.z*rw02 + nv.w*rw03;
        float f1 = nv.x*rw10 + nv.y*rw11 + nv.z*rw12 + nv.w*rw13;
        float f2 = nv.x*rw20 + nv.y*rw21 + nv.z*rw22 + nv.w*rw23;
        float f3 = nv.x*rw30 + nv.y*rw31 + nv.z*rw32 + nv.w*rw33;
        f0 = wsum_(f0); f1 = wsum_(f1); f2 = wsum_(f2); f3 = wsum_(f3);
        if (lane == 0) { fwdl[i] = f0; fwdl[256+i] = f1; fwdl[512+i] = f2; fwdl[768+i] = f3; }
        float ri0 = rwl[i], ri1 = rwl[256+i], ri2 = rwl[512+i], ri3 = rwl[768+i];
        ba0.x = fmaf(ri0, nv.x, ba0.x); ba0.y = fmaf(ri0, nv.y, ba0.y);
        ba0.z = fmaf(ri0, nv.z, ba0.z); ba0.w = fmaf(ri0, nv.w, ba0.w);
        ba1.x = fmaf(ri1, nv.x, ba1.x); ba1.y = fmaf(ri1, nv.y, ba1.y);
        ba1.z = fmaf(ri1, nv.z, ba1.z); ba1.w = fmaf(ri1, nv.w, ba1.w);
        ba2.x = fmaf(ri2, nv.x, ba2.x); ba2.y = fmaf(ri2, nv.y, ba2.y);
        ba2.z = fmaf(ri2, nv.z, ba2.z); ba2.w = fmaf(ri2, nv.w, ba2.w);
        ba3.x = fmaf(ri3, nv.x, ba3.x); ba3.y = fmaf(ri3, nv.y, ba3.y);
        ba3.z = fmaf(ri3, nv.z, ba3.z); ba3.w = fmaf(ri3, nv.w, ba3.w);
      }
#pragma unroll
      for (int r = 0; r < 4; r++) {
        float4 v = (r==0) ? ba0 : (r==1) ? ba1 : (r==2) ? ba2 : ba3;
        *(float4*)&bb[wv][j0] = v;
        __syncthreads();
        if (tid < 256) {
          float s = 0.f;
#pragma unroll
          for (int w2 = 0; w2 < 16; w2++) s += bb[w2][tid];
          bwdl[r*256 + tid] = s;
        }
        __syncthreads();
      }
    }
    if (tid < 256) pOl[tid] = pNl[tid];

    // ---- M update + rc logits (NEW M) ----
    {
      int n = tid >> 2, q = tid & 3;
      float wwn = wwl[n];
      float4* Mp = (float4*)(Mg + n*64 + q*16);
      float ss = 0.f, d0 = 0.f, d1 = 0.f, d2 = 0.f, d3 = 0.f;
#pragma unroll
      for (int i = 0; i < 4; i++) {
        float4 mv = Mp[i];
        int w0 = q*16 + i*4;
        float4 ev = *(const float4*)(evl + w0);
        float4 wq = *(const float4*)(wvl + w0);
        float4 nv;
        nv.x = mv.x*(1.f - wwn*ev.x) + wwn*wq.x;
        nv.y = mv.y*(1.f - wwn*ev.y) + wwn*wq.y;
        nv.z = mv.z*(1.f - wwn*ev.z) + wwn*wq.z;
        nv.w = mv.w*(1.f - wwn*ev.w) + wwn*wq.w;
        Mp[i] = nv;
        ss += nv.x*nv.x + nv.y*nv.y + nv.z*nv.z + nv.w*nv.w;
        const float* k0 = rknl + w0;
        const float* k1 = rknl + 64 + w0;
        const float* k2 = rknl + 128 + w0;
        const float* k3 = rknl + 192 + w0;
        d0 += nv.x*k0[0] + nv.y*k0[1] + nv.z*k0[2] + nv.w*k0[3];
        d1 += nv.x*k1[0] + nv.y*k1[1] + nv.z*k1[2] + nv.w*k1[3];
        d2 += nv.x*k2[0] + nv.y*k2[1] + nv.z*k2[2] + nv.w*k2[3];
        d3 += nv.x*k3[0] + nv.y*k3[1] + nv.z*k3[2] + nv.w*k3[3];
      }
      ss += __shfl_xor(ss,1,64); ss += __shfl_xor(ss,2,64);
      d0 += __shfl_xor(d0,1,64); d0 += __shfl_xor(d0,2,64);
      d1 += __shfl_xor(d1,1,64); d1 += __shfl_xor(d1,2,64);
      d2 += __shfl_xor(d2,1,64); d2 += __shfl_xor(d2,2,64);
      d3 += __shfl_xor(d3,1,64); d3 += __shfl_xor(d3,2,64);
      if (q == 0) {
        float inv = 1.f/(sqrtf(ss) + EPS_);
        rcs[n]     = oneplusf_(ifcl[OFF_RB+0]) * d0 * inv;
        rcs[256+n] = oneplusf_(ifcl[OFF_RB+1]) * d1 * inv;
        rcs[512+n] = oneplusf_(ifcl[OFF_RB+2]) * d2 * inv;
        rcs[768+n] = oneplusf_(ifcl[OFF_RB+3]) * d3 * inv;
      }
    }
    __syncthreads();

    // ---- rc softmax ----
    if (wv < 4) {
      float* rp = rcs + wv*256;
      float v0 = rp[lane], v1 = rp[64+lane], v2 = rp[128+lane], v3 = rp[192+lane];
      float mx = wmax_(fmaxf(fmaxf(v0,v1), fmaxf(v2,v3)));
      float e0 = expf(v0-mx), e1 = expf(v1-mx), e2 = expf(v2-mx), e3 = expf(v3-mx);
      float inv = 1.f / wsum_(e0+e1+e2+e3);
      rp[lane] = e0*inv; rp[64+lane] = e1*inv; rp[128+lane] = e2*inv; rp[192+lane] = e3*inv;
    }
    __syncthreads();

    // ---- rw_new ----
    {
      int r = tid >> 8;
      float e0 = ifcl[OFF_RM + r*3+0], e1 = ifcl[OFF_RM + r*3+1], e2 = ifcl[OFF_RM + r*3+2];
      float mx = fmaxf(e0, fmaxf(e1, e2));
      float x0 = expf(e0-mx), x1 = expf(e1-mx), x2 = expf(e2-mx);
      float inv = 1.f/(x0+x1+x2);
      rwl[tid] = (x0*bwdl[tid] + x1*rcs[tid] + x2*fwdl[tid]) * inv;
    }
    __syncthreads();

    // ---- rv_new ----
    {
      int w = tid & 63, r = (tid >> 6) & 3, c = tid >> 8;
      const float* rp = rwl + r*256 + c*64;
      float acc = 0.f;
#pragma unroll 8
      for (int n = 0; n < 64; n++) acc = fmaf(Mg[(c*64+n)*64 + w], rp[n], acc);
      psum[c*256 + r*64 + w] = acc;
    }
    __syncthreads();
    if (tid < 256) {
      float v = psum[tid] + psum[256+tid] + psum[512+tid] + psum[768+tid];
      rvl[tid] = v;
      rvs[(size_t)(t*16 + b)*256 + tid] = v;    // save for deferred out GEMM
    }
    __syncthreads();

    // ---- h(t+1) = relu(hx(t+1) + rv @ W_hid[512:768] bf16 uint4) ----
    if (t + 1 < TS) {
      int col = tid & 511, kseg = tid >> 9;
      const uint4* Wp = (const uint4*)(WhpT + col*WHPS + kseg*64);
      const float* rp = rvl + kseg*128;
      float acc = 0.f;
#pragma unroll 8
      for (int q4 = 0; q4 < 16; q4++) acc = dot8_(Wp[q4], rp + q4*8, acc);
      psum[tid] = acc;
      __syncthreads();
      if (tid < 512)
        hl[tid] = fmaxf(hx[(size_t)((t+1)*16 + b)*512 + tid] + psum[tid] + psum[512+tid], 0.f);
      __syncthreads();
    }
  }
}

// ===================== kOut: out(t) = h(t)@W_out + rv(t)@W_memout (all t) =========
// 256 blocks x 1024: block = (rowgroup of 16 rows) x (col-quarter of 128)
__global__ void __launch_bounds__(1024)
kOut(const float* __restrict__ W_out, const float* __restrict__ W_memout,
     const float* __restrict__ hsv, const float* __restrict__ rvs,
     float* __restrict__ out)
{
  const int tid = threadIdx.x, blk = blockIdx.x;
  const int rg = blk >> 2, cq = blk & 3;
  __shared__ float hs[16*512];
  __shared__ float rs[16*256];
  for (int i = tid; i < 16*512; i += 1024) hs[i] = hsv[(size_t)rg*16*512 + i];
  for (int i = tid; i < 16*256; i += 1024) rs[i] = rvs[(size_t)rg*16*256 + i];
  __syncthreads();
  int c  = cq*128 + (tid & 127);
  int ro = tid >> 7;                    // 0..7 -> rows 2*ro, 2*ro+1
  const float* h0 = hs + (2*ro)*512;
  const float* h1 = h0 + 512;
  const float* r0 = rs + (2*ro)*256;
  const float* r1 = r0 + 256;
  float a0 = 0.f, a1 = 0.f;
  const float* Wp = W_out + c;
#pragma unroll 8
  for (int k = 0; k < 512; k++) {
    float w = Wp[(size_t)k*512];
    a0 = fmaf(h0[k], w, a0);
    a1 = fmaf(h1[k], w, a1);
  }
  const float* Wm = W_memout + c;
#pragma unroll 8
  for (int k = 0; k < 256; k++) {
    float w = Wm[(size_t)k*512];
    a0 = fmaf(r0[k], w, a0);
    a1 = fmaf(r1[k], w, a1);
  }
  out[(size_t)(rg*16 + 2*ro)*512 + c]     = a0;
  out[(size_t)(rg*16 + 2*ro + 1)*512 + c] = a1;
}

extern "C" void kernel_launch(void* const* d_in, const int* in_sizes, int n_in,
                              void* d_out, int out_size, void* d_ws, size_t ws_size,
                              hipStream_t stream) {
  (void)in_sizes; (void)n_in; (void)out_size; (void)ws_size;
  const float* x        = (const float*)d_in[0];
  const float* W_hid    = (const float*)d_in[1];
  const float* b_hid    = (const float*)d_in[2];
  const float* W_iface  = (const float*)d_in[3];
  const float* W_out    = (const float*)d_in[4];
  const float* W_memout = (const float*)d_in[5];
  float* outp = (float*)d_out;
  float* ws   = (float*)d_ws;

  hipLaunchKernelGGL(kInit, dim3(256), dim3(256), 0, stream, ws);
  hipLaunchKernelGGL(kConv, dim3(256), dim3(256), 0, stream, W_hid, W_iface, ws);
  hipLaunchKernelGGL(kPre,  dim3(256), dim3(256), 0, stream, x, W_hid, b_hid, ws);

  const unsigned* WipT = (const unsigned*)(ws + O_WIP);
  const unsigned* WhpT = (const unsigned*)(ws + O_WHP);
  float* hx   = ws + O_HX;
  float* rvs  = ws + O_RS;
  float* Mall = ws + O_M;
  float* Lall = ws + O_L;

  hipLaunchKernelGGL(kLoop, dim3(16), dim3(1024), 0, stream,
                     WipT, WhpT, hx, rvs, Mall, Lall);
  hipLaunchKernelGGL(kOut, dim3(256), dim3(1024), 0, stream,
                     W_out, W_memout, hx, rvs, outp);
}

// Round 12
// 3411.500 us; speedup vs baseline: 1.5815x; 1.0256x over previous
//
#include <hip/hip_runtime.h>
#include <math.h>

#define TS 64
#define IFACE_N 471
#define EPS_ 1e-6f

// iface column offsets
#define OFF_RK 0
#define OFF_RB 256
#define OFF_WK 260
#define OFF_WB 324
#define OFF_EV 325
#define OFF_WV 389
#define OFF_FG 453
#define OFF_AG 457
#define OFF_WG 458
#define OFF_RM 459

// ws float offsets
#define O_HX   0         // 524288 : hx[t*16+b][512]; overwritten in-place with h(t)
#define O_RS   524288    // 262144 : rv(t) save (t*16+b)x256
#define O_L    1048576   // 1048576 (M now lives in LDS)
// packed bf16 weights, transposed [col][kpair], padded strides:
#define WIPS 260
#define WHPS 132
#define O_WIP  2097152   // 471*260 = 122460 uints   W_iface (256 kp)
#define O_WHP  2219612   // 512*132 = 67584          W_hid[512:768] (128 kp)
// total 2,287,196 floats = 9.15 MB

__device__ __forceinline__ float sigmoidf_(float x){ return 1.f/(1.f+expf(-x)); }
__device__ __forceinline__ float oneplusf_(float x){ return 1.f+fmaxf(x,0.f)+log1pf(expf(-fabsf(x))); }
__device__ __forceinline__ float wsum_(float v){
#pragma unroll
  for(int off=32; off>0; off>>=1) v += __shfl_xor(v,off,64);
  return v;
}
__device__ __forceinline__ float wmax_(float v){
#pragma unroll
  for(int off=32; off>0; off>>=1) v = fmaxf(v,__shfl_xor(v,off,64));
  return v;
}
__device__ __forceinline__ unsigned bf16rne_(float f){
  unsigned u = __float_as_uint(f);
  return (u + 0x7FFFu + ((u >> 16) & 1u)) >> 16;
}
__device__ __forceinline__ unsigned bf16pack_(float lo, float hi){
  return bf16rne_(lo) | (bf16rne_(hi) << 16);
}
__device__ __forceinline__ float bflo_(unsigned p){ return __uint_as_float(p << 16); }
__device__ __forceinline__ float bfhi_(unsigned p){ return __uint_as_float(p & 0xFFFF0000u); }

__device__ __forceinline__ float dot8_(uint4 p, const float* a, float acc){
  acc = fmaf(a[0], bflo_(p.x), acc); acc = fmaf(a[1], bfhi_(p.x), acc);
  acc = fmaf(a[2], bflo_(p.y), acc); acc = fmaf(a[3], bfhi_(p.y), acc);
  acc = fmaf(a[4], bflo_(p.z), acc); acc = fmaf(a[5], bfhi_(p.z), acc);
  acc = fmaf(a[6], bflo_(p.w), acc); acc = fmaf(a[7], bfhi_(p.w), acc);
  return acc;
}

// ===================== init (L only; M is in LDS now) =====================
__global__ void __launch_bounds__(256) kInit(float* ws){
  int g = blockIdx.x*256 + threadIdx.x;          // 65536 threads
  for (int i=g;i<1048576;i+=65536) ws[O_L+i]=0.f;
}

// ===================== kConv: pack + transpose recurrent-path weights =============
__global__ void __launch_bounds__(256)
kConv(const float* __restrict__ W_hid, const float* __restrict__ W_iface,
      float* __restrict__ ws)
{
  unsigned* Wip = (unsigned*)(ws + O_WIP);
  unsigned* Whp = (unsigned*)(ws + O_WHP);
  int g = blockIdx.x*256 + threadIdx.x;          // 65536 threads
  for (int i = g; i < 471*256; i += 65536) {
    int c = i >> 8, kp = i & 255;
    Wip[c*WIPS + kp] = bf16pack_(W_iface[(size_t)(2*kp)*IFACE_N + c],
                                 W_iface[(size_t)(2*kp+1)*IFACE_N + c]);
  }
  {
    int c = g >> 7, kp = g & 127;
    Whp[c*WHPS + kp] = bf16pack_(W_hid[(size_t)(512 + 2*kp)*512 + c],
                                 W_hid[(size_t)(513 + 2*kp)*512 + c]);
  }
}

// ===================== kPre: hx = x @ W_hid[0:512] + b =====================
__global__ void __launch_bounds__(256)
kPre(const float* __restrict__ x, const float* __restrict__ W_hid,
     const float* __restrict__ b_hid, float* __restrict__ ws)
{
  const int tid = threadIdx.x, blk = blockIdx.x;
  const int r0 = (blk >> 1) * 8, col = (blk & 1) * 256 + tid;
  __shared__ float xs[8][512];
  for (int i = tid; i < 8*512; i += 256) {
    int rr = i >> 9, k = i & 511;
    xs[rr][k] = x[(size_t)(r0+rr)*512 + k];
  }
  __syncthreads();
  float a0=0,a1=0,a2=0,a3=0,a4=0,a5=0,a6=0,a7=0;
  const float* Wp = W_hid + col;
#pragma unroll 4
  for (int k = 0; k < 512; k++) {
    float w = Wp[(size_t)k*512];
    a0 = fmaf(xs[0][k], w, a0); a1 = fmaf(xs[1][k], w, a1);
    a2 = fmaf(xs[2][k], w, a2); a3 = fmaf(xs[3][k], w, a3);
    a4 = fmaf(xs[4][k], w, a4); a5 = fmaf(xs[5][k], w, a5);
    a6 = fmaf(xs[6][k], w, a6); a7 = fmaf(xs[7][k], w, a7);
  }
  float bh = b_hid[col];
  float av[8] = {a0,a1,a2,a3,a4,a5,a6,a7};
#pragma unroll
  for (int i = 0; i < 8; i++)
    ws[O_HX + (size_t)(r0+i)*512 + col] = av[i] + bh;
}

// ===================== kLoop: 16 independent per-batch blocks, all 64 steps =======
__global__ void __launch_bounds__(1024, 4)
kLoop(const unsigned* __restrict__ WipT, const unsigned* __restrict__ WhpT,
      float* __restrict__ hx, float* __restrict__ rvs, float* __restrict__ Lall)
{
  const int tid = threadIdx.x, b = blockIdx.x;
  const int wv = tid >> 6, lane = tid & 63;

  __shared__ float hl[512];
  __shared__ float ifcl[480];
  __shared__ float psum[1024];
  __shared__ float ul[256], pOl[256], pNl[256], wwl[256];
  __shared__ float rwl[1024];
  __shared__ float wkn[64], rknl[256];
  __shared__ alignas(16) float evl[64], wvl[64];
  __shared__ float ssorted[256];
  __shared__ int   sidx[256];
  __shared__ float sal[256], siml[256], cwl[256];
  __shared__ float fwdl[1024], bwdl[1024], rcs[1024];
  __shared__ alignas(16) float bb[16][260];
  __shared__ float rvl[256];
  __shared__ alignas(16) float Ml[16384];    // M lives in LDS (block-private)

  float* Lg = Lall + (size_t)b*65536;

  if (tid < 512) hl[tid] = fmaxf(hx[(size_t)b*512 + tid], 0.f);   // h(0)
  rwl[tid] = 0.f;
  if (tid < 256){ ul[tid]=0.f; pOl[tid]=0.f; wwl[tid]=0.f; }
  for (int i = tid; i < 16384; i += 1024) Ml[i] = 1e-6f;
  __syncthreads();

  for (int t = 0; t < TS; t++) {
    // ---- save h(t) for the deferred output GEMM (overwrites consumed hx[t]) ----
    if (tid < 512) hx[(size_t)(t*16 + b)*512 + tid] = hl[tid];

    // ---- iface = h @ W_iface (bf16 uint4, k-split 2) ----
    {
      int col = tid & 511, kseg = tid >> 9;
      float acc = 0.f;
      if (col < IFACE_N) {
        const uint4* Wp = (const uint4*)(WipT + col*WIPS + kseg*128);
        const float* hp = hl + kseg*256;
#pragma unroll 8
        for (int q4 = 0; q4 < 32; q4++) acc = dot8_(Wp[q4], hp + q4*8, acc);
      }
      psum[tid] = acc;
    }
    __syncthreads();
    if (tid < IFACE_N) ifcl[tid] = psum[tid] + psum[512+tid];
    __syncthreads();

    // ---- usage update + key norms + gate vectors ----
    if (tid < 256) {
      float ret = 1.f;
#pragma unroll
      for (int r = 0; r < 4; r++) {
        float fg = sigmoidf_(ifcl[OFF_FG + r]);
        ret *= (1.f - fg * rwl[r*256 + tid]);
      }
      float uo = ul[tid], wo = wwl[tid];
      ul[tid] = (uo + wo - uo*wo) * ret;
    } else if (tid >= 448 && tid < 512) {              // wave 7: wk norm
      float kv = ifcl[OFF_WK + lane];
      float ss = wsum_(kv*kv);
      wkn[lane] = kv / (sqrtf(ss) + EPS_);
    } else if (tid >= 512 && tid < 768) {              // waves 8..11: rk norms
      int r = wv - 8;
      float kv = ifcl[OFF_RK + r*64 + lane];
      float ss = wsum_(kv*kv);
      rknl[r*64 + lane] = kv / (sqrtf(ss) + EPS_);
    } else if (tid >= 768 && tid < 832) {              // wave 12: erase vec
      evl[lane] = sigmoidf_(ifcl[OFF_EV + lane]);
    } else if (tid >= 832 && tid < 896) {              // wave 13: write vec
      wvl[lane] = ifcl[OFF_WV + lane];
    }
    __syncthreads();

    // ---- MERGED: stable rank argsort + content-dot over OLD M (independent) ----
    {
      int n = tid >> 2, q = tid & 3;
      const float4* Mp = (const float4*)(Ml + n*64 + q*16);
      float4 m0 = Mp[0], m1 = Mp[1], m2 = Mp[2], m3 = Mp[3];
      // rank count (LDS ul reads overlap the M-dot chain)
      float un = ul[n];
      const float* sp = ul + q*64;
      int cnt = 0;
#pragma unroll 8
      for (int m = 0; m < 64; m++) {
        float um = sp[m];
        int gm = q*64 + m;
        cnt += (um < un || (um == un && gm < n)) ? 1 : 0;
      }
      cnt += __shfl_xor(cnt, 1, 64);
      cnt += __shfl_xor(cnt, 2, 64);
      // content dot
      const float* kp = wkn + q*16;
      float ss = m0.x*m0.x + m0.y*m0.y + m0.z*m0.z + m0.w*m0.w
               + m1.x*m1.x + m1.y*m1.y + m1.z*m1.z + m1.w*m1.w
               + m2.x*m2.x + m2.y*m2.y + m2.z*m2.z + m2.w*m2.w
               + m3.x*m3.x + m3.y*m3.y + m3.z*m3.z + m3.w*m3.w;
      float dt = m0.x*kp[0] + m0.y*kp[1] + m0.z*kp[2] + m0.w*kp[3]
               + m1.x*kp[4] + m1.y*kp[5] + m1.z*kp[6] + m1.w*kp[7]
               + m2.x*kp[8] + m2.y*kp[9] + m2.z*kp[10] + m2.w*kp[11]
               + m3.x*kp[12] + m3.y*kp[13] + m3.z*kp[14] + m3.w*kp[15];
      ss += __shfl_xor(ss,1,64); ss += __shfl_xor(ss,2,64);
      dt += __shfl_xor(dt,1,64); dt += __shfl_xor(dt,2,64);
      if (q == 0) {
        ssorted[cnt] = un; sidx[cnt] = n;
        float wb = oneplusf_(ifcl[OFF_WB]);
        siml[n] = wb * dt / (sqrtf(ss) + EPS_);
      }
    }
    __syncthreads();

    // ---- PARALLEL: cumprod alloc (wave 0) | write softmax (waves 4..7) ----
    if (wv == 0) {
      float carry = 1.f;
#pragma unroll
      for (int c2 = 0; c2 < 4; c2++) {
        float v0 = ssorted[c2*64 + lane];
        float v = v0;
#pragma unroll
        for (int off = 1; off < 64; off <<= 1) {
          float uu = __shfl_up(v, off, 64);
          if (lane >= off) v *= uu;
        }
        float e = __shfl_up(v, 1, 64);
        if (lane == 0) e = 1.f;
        sal[sidx[c2*64 + lane]] = (1.f - v0) * e * carry;
        carry *= __shfl(v, 63, 64);
      }
    } else if (wv >= 4 && wv < 8) {
      int s = tid - 256;                   // 0..255
      float v0 = siml[lane], v1 = siml[64+lane], v2 = siml[128+lane], v3 = siml[192+lane];
      float mx = wmax_(fmaxf(fmaxf(v0,v1), fmaxf(v2,v3)));
      float ssum = wsum_(expf(v0-mx)+expf(v1-mx)+expf(v2-mx)+expf(v3-mx));
      cwl[s] = expf(siml[s]-mx) / ssum;
    }
    __syncthreads();

    // ---- ww ----
    if (tid < 256) {
      float ag = sigmoidf_(ifcl[OFF_AG]);
      float wg = sigmoidf_(ifcl[OFF_WG]);
      float wwn = wg * (ag*sal[tid] + (1.f-ag)*cwl[tid]);
      wwl[tid] = wwn;
      ssorted[tid] = wwn;                  // scratch for wws reduce
    }
    __syncthreads();
    if (tid < 256) {
      float s4 = ssorted[lane] + ssorted[64+lane] + ssorted[128+lane] + ssorted[192+lane];
      float wws = wsum_(s4);
      pNl[tid] = (1.f - wws)*pOl[tid] + wwl[tid];
    }
    __syncthreads();

    // ---- L update + fwd + bwd ----
    {
      int j0 = lane*4;
      float wwj0 = wwl[j0], wwj1 = wwl[j0+1], wwj2 = wwl[j0+2], wwj3 = wwl[j0+3];
      float pj0 = pOl[j0], pj1 = pOl[j0+1], pj2 = pOl[j0+2], pj3 = pOl[j0+3];
      float rw00 = rwl[j0],     rw01 = rwl[j0+1],     rw02 = rwl[j0+2],     rw03 = rwl[j0+3];
      float rw10 = rwl[256+j0], rw11 = rwl[256+j0+1], rw12 = rwl[256+j0+2], rw13 = rwl[256+j0+3];
      float rw20 = rwl[512+j0], rw21 = rwl[512+j0+1], rw22 = rwl[512+j0+2], rw23 = rwl[512+j0+3];
      float rw30 = rwl[768+j0], rw31 = rwl[768+j0+1], rw32 = rwl[768+j0+2], rw33 = rwl[768+j0+3];
      float4 ba0 = {0,0,0,0}, ba1 = {0,0,0,0}, ba2 = {0,0,0,0}, ba3 = {0,0,0,0};
      float4* Lrow = (float4*)Lg;
#pragma unroll 4
      for (int ii = 0; ii < 16; ii++) {
        int i = wv*16 + ii;
        float wwi = wwl[i];
        float4 lv = Lrow[i*64 + lane];
        float4 nv;
        nv.x = (1.f - wwi - wwj0)*lv.x + wwi*pj0;
        nv.y = (1.f - wwi - wwj1)*lv.y + wwi*pj1;
        nv.z = (1.f - wwi - wwj2)*lv.z + wwi*pj2;
        nv.w = (1.f - wwi - wwj3)*lv.w + wwi*pj3;
        if (j0   == i) nv.x = 0.f;
        if (j0+1 == i) nv.y = 0.f;
        if (j0+2 == i) nv.z = 0.f;
        if (j0+3 == i) nv.w = 0.f;
        Lrow[i*64 + lane] = nv;
        float f0 = nv.x*rw00 + nv.y*rw01 + nv.z*rw02 + nv.w*rw03;
        float f1 = nv.x*rw10 + nv.y*rw11 + nv.z*rw12 + nv.w*rw13;
        float f2 = nv.x*rw20 + nv.y*rw21 + nv.z*rw22 + nv.w*rw23;
        float f3 = nv.x*rw30 + nv.y*rw31 + nv.z*rw32 + nv.w*rw33;
        f0 = wsum_(f0); f1 = wsum_(f1); f2 = wsum_(f2); f3 = wsum_(f3);
        if (lane == 0) { fwdl[i] = f0; fwdl[256+i] = f1; fwdl[512+i] = f2; fwdl[768+i] = f3; }
        float ri0 = rwl[i], ri1 = rwl[256+i], ri2 = rwl[512+i], ri3 = rwl[768+i];
        ba0.x = fmaf(ri0, nv.x, ba0.x); ba0.y = fmaf(ri0, nv.y, ba0.y);
        ba0.z = fmaf(ri0, nv.z, ba0.z); ba0.w = fmaf(ri0, nv.w, ba0.w);
        ba1.x = fmaf(ri1, nv.x, ba1.x); ba1.y = fmaf(ri1, nv.y, ba1.y);
        ba1.z = fmaf(ri1, nv.z, ba1.z); ba1.w = fmaf(ri1, nv.w, ba1.w);
        ba2.x = fmaf(ri2, nv.x, ba2.x); ba2.y = fmaf(ri2, nv.y, ba2.y);
        ba2.z = fmaf(ri2, nv.z, ba2.z); ba2.w = fmaf(ri2, nv.w, ba2.w);
        ba3.x = fmaf(ri3, nv.x, ba3.x); ba3.y = fmaf(ri3, nv.y, ba3.y);
        ba3.z = fmaf(ri3, nv.z, ba3.z); ba3.w = fmaf(ri3, nv.w, ba3.w);
      }
#pragma unroll
      for (int r = 0; r < 4; r++) {
        float4 v = (r==0) ? ba0 : (r==1) ? ba1 : (r==2) ? ba2 : ba3;
        *(float4*)&bb[wv][j0] = v;
        __syncthreads();
        if (tid < 256) {
          float s = 0.f;
#pragma unroll
          for (int w2 = 0; w2 < 16; w2++) s += bb[w2][tid];
          bwdl[r*256 + tid] = s;
        }
        __syncthreads();
      }
    }
    if (tid < 256) pOl[tid] = pNl[tid];

    // ---- M update + rc logits (NEW M, in LDS) ----
    {
      int n = tid >> 2, q = tid & 3;
      float wwn = wwl[n];
      float4* Mp = (float4*)(Ml + n*64 + q*16);
      float ss = 0.f, d0 = 0.f, d1 = 0.f, d2 = 0.f, d3 = 0.f;
#pragma unroll
      for (int i = 0; i < 4; i++) {
        float4 mv = Mp[i];
        int w0 = q*16 + i*4;
        float4 ev = *(const float4*)(evl + w0);
        float4 wq = *(const float4*)(wvl + w0);
        float4 nv;
        nv.x = mv.x*(1.f - wwn*ev.x) + wwn*wq.x;
        nv.y = mv.y*(1.f - wwn*ev.y) + wwn*wq.y;
        nv.z = mv.z*(1.f - wwn*ev.z) + wwn*wq.z;
        nv.w = mv.w*(1.f - wwn*ev.w) + wwn*wq.w;
        Mp[i] = nv;
        ss += nv.x*nv.x + nv.y*nv.y + nv.z*nv.z + nv.w*nv.w;
        const float* k0 = rknl + w0;
        const float* k1 = rknl + 64 + w0;
        const float* k2 = rknl + 128 + w0;
        const float* k3 = rknl + 192 + w0;
        d0 += nv.x*k0[0] + nv.y*k0[1] + nv.z*k0[2] + nv.w*k0[3];
        d1 += nv.x*k1[0] + nv.y*k1[1] + nv.z*k1[2] + nv.w*k1[3];
        d2 += nv.x*k2[0] + nv.y*k2[1] + nv.z*k2[2] + nv.w*k2[3];
        d3 += nv.x*k3[0] + nv.y*k3[1] + nv.z*k3[2] + nv.w*k3[3];
      }
      ss += __shfl_xor(ss,1,64); ss += __shfl_xor(ss,2,64);
      d0 += __shfl_xor(d0,1,64); d0 += __shfl_xor(d0,2,64);
      d1 += __shfl_xor(d1,1,64); d1 += __shfl_xor(d1,2,64);
      d2 += __shfl_xor(d2,1,64); d2 += __shfl_xor(d2,2,64);
      d3 += __shfl_xor(d3,1,64); d3 += __shfl_xor(d3,2,64);
      if (q == 0) {
        float inv = 1.f/(sqrtf(ss) + EPS_);
        rcs[n]     = oneplusf_(ifcl[OFF_RB+0]) * d0 * inv;
        rcs[256+n] = oneplusf_(ifcl[OFF_RB+1]) * d1 * inv;
        rcs[512+n] = oneplusf_(ifcl[OFF_RB+2]) * d2 * inv;
        rcs[768+n] = oneplusf_(ifcl[OFF_RB+3]) * d3 * inv;
      }
    }
    __syncthreads();

    // ---- rc softmax ----
    if (wv < 4) {
      float* rp = rcs + wv*256;
      float v0 = rp[lane], v1 = rp[64+lane], v2 = rp[128+lane], v3 = rp[192+lane];
      float mx = wmax_(fmaxf(fmaxf(v0,v1), fmaxf(v2,v3)));
      float e0 = expf(v0-mx), e1 = expf(v1-mx), e2 = expf(v2-mx), e3 = expf(v3-mx);
      float inv = 1.f / wsum_(e0+e1+e2+e3);
      rp[lane] = e0*inv; rp[64+lane] = e1*inv; rp[128+lane] = e2*inv; rp[192+lane] = e3*inv;
    }
    __syncthreads();

    // ---- rw_new ----
    {
      int r = tid >> 8;
      float e0 = ifcl[OFF_RM + r*3+0], e1 = ifcl[OFF_RM + r*3+1], e2 = ifcl[OFF_RM + r*3+2];
      float mx = fmaxf(e0, fmaxf(e1, e2));
      float x0 = expf(e0-mx), x1 = expf(e1-mx), x2 = expf(e2-mx);
      float inv = 1.f/(x0+x1+x2);
      rwl[tid] = (x0*bwdl[tid] + x1*rcs[tid] + x2*fwdl[tid]) * inv;
    }
    __syncthreads();

    // ---- rv_new (M from LDS) ----
    {
      int w = tid & 63, r = (tid >> 6) & 3, c = tid >> 8;
      const float* rp = rwl + r*256 + c*64;
      float acc = 0.f;
#pragma unroll 8
      for (int n = 0; n < 64; n++) acc = fmaf(Ml[(c*64+n)*64 + w], rp[n], acc);
      psum[c*256 + r*64 + w] = acc;
    }
    __syncthreads();
    if (tid < 256) {
      float v = psum[tid] + psum[256+tid] + psum[512+tid] + psum[768+tid];
      rvl[tid] = v;
      rvs[(size_t)(t*16 + b)*256 + tid] = v;    // save for deferred out GEMM
    }
    __syncthreads();

    // ---- h(t+1) = relu(hx(t+1) + rv @ W_hid[512:768] bf16 uint4) ----
    if (t + 1 < TS) {
      int col = tid & 511, kseg = tid >> 9;
      const uint4* Wp = (const uint4*)(WhpT + col*WHPS + kseg*64);
      const float* rp = rvl + kseg*128;
      float acc = 0.f;
#pragma unroll 8
      for (int q4 = 0; q4 < 16; q4++) acc = dot8_(Wp[q4], rp + q4*8, acc);
      psum[tid] = acc;
      __syncthreads();
      if (tid < 512)
        hl[tid] = fmaxf(hx[(size_t)((t+1)*16 + b)*512 + tid] + psum[tid] + psum[512+tid], 0.f);
      __syncthreads();
    }
  }
}

// ===================== kOut: out(t) = h(t)@W_out + rv(t)@W_memout (all t) =========
__global__ void __launch_bounds__(1024)
kOut(const float* __restrict__ W_out, const float* __restrict__ W_memout,
     const float* __restrict__ hsv, const float* __restrict__ rvs,
     float* __restrict__ out)
{
  const int tid = threadIdx.x, blk = blockIdx.x;
  const int rg = blk >> 2, cq = blk & 3;
  __shared__ float hs[16*512];
  __shared__ float rs[16*256];
  for (int i = tid; i < 16*512; i += 1024) hs[i] = hsv[(size_t)rg*16*512 + i];
  for (int i = tid; i < 16*256; i += 1024) rs[i] = rvs[(size_t)rg*16*256 + i];
  __syncthreads();
  int c  = cq*128 + (tid & 127);
  int ro = tid >> 7;                    // 0..7 -> rows 2*ro, 2*ro+1
  const float* h0 = hs + (2*ro)*512;
  const float* h1 = h0 + 512;
  const float* r0 = rs + (2*ro)*256;
  const float* r1 = r0 + 256;
  float a0 = 0.f, a1 = 0.f;
  const float* Wp = W_out + c;
#pragma unroll 8
  for (int k = 0; k < 512; k++) {
    float w = Wp[(size_t)k*512];
    a0 = fmaf(h0[k], w, a0);
    a1 = fmaf(h1[k], w, a1);
  }
  const float* Wm = W_memout + c;
#pragma unroll 8
  for (int k = 0; k < 256; k++) {
    float w = Wm[(size_t)k*512];
    a0 = fmaf(r0[k], w, a0);
    a1 = fmaf(r1[k], w, a1);
  }
  out[(size_t)(rg*16 + 2*ro)*512 + c]     = a0;
  out[(size_t)(rg*16 + 2*ro + 1)*512 + c] = a1;
}

extern "C" void kernel_launch(void* const* d_in, const int* in_sizes, int n_in,
                              void* d_out, int out_size, void* d_ws, size_t ws_size,
                              hipStream_t stream) {
  (void)in_sizes; (void)n_in; (void)out_size; (void)ws_size;
  const float* x        = (const float*)d_in[0];
  const float* W_hid    = (const float*)d_in[1];
  const float* b_hid    = (const float*)d_in[2];
  const float* W_iface  = (const float*)d_in[3];
  const float* W_out    = (const float*)d_in[4];
  const float* W_memout = (const float*)d_in[5];
  float* outp = (float*)d_out;
  float* ws   = (float*)d_ws;

  hipLaunchKernelGGL(kInit, dim3(256), dim3(256), 0, stream, ws);
  hipLaunchKernelGGL(kConv, dim3(256), dim3(256), 0, stream, W_hid, W_iface, ws);
  hipLaunchKernelGGL(kPre,  dim3(256), dim3(256), 0, stream, x, W_hid, b_hid, ws);

  const unsigned* WipT = (const unsigned*)(ws + O_WIP);
  const unsigned* WhpT = (const unsigned*)(ws + O_WHP);
  float* hx   = ws + O_HX;
  float* rvs  = ws + O_RS;
  float* Lall = ws + O_L;

  hipLaunchKernelGGL(kLoop, dim3(16), dim3(1024), 0, stream,
                     WipT, WhpT, hx, rvs, Lall);
  hipLaunchKernelGGL(kOut, dim3(256), dim3(1024), 0, stream,
                     W_out, W_memout, hx, rvs, outp);
}